// Round 10
// baseline (323.413 us; speedup 1.0000x reference)
//
#include <hip/hip_runtime.h>
#include <stdint.h>
#include <math.h>

// B=2 S=2048 E=1024 H=16 DH=64 ROT=32 CTX=2048
// d_in / d_out are FLOAT32 (per reference). Internals use bf16 MFMA.
typedef __bf16 bf16x8 __attribute__((ext_vector_type(8)));
typedef float f32x4 __attribute__((ext_vector_type(4)));

__device__ __forceinline__ float bf2f(uint16_t x) {
  unsigned u = ((unsigned)x) << 16;
  float f;
  __builtin_memcpy(&f, &u, 4);
  return f;
}
// native RTNE f32->bf16
__device__ __forceinline__ uint16_t f2bf(float f) {
  __bf16 h = (__bf16)f;
  uint16_t u;
  __builtin_memcpy(&u, &h, 2);
  return u;
}
// round two float4s to bf16x8
__device__ __forceinline__ bf16x8 pack8(float4 lo, float4 hi) {
  bf16x8 v;
  v[0] = (__bf16)lo.x; v[1] = (__bf16)lo.y; v[2] = (__bf16)lo.z; v[3] = (__bf16)lo.w;
  v[4] = (__bf16)hi.x; v[5] = (__bf16)hi.y; v[6] = (__bf16)hi.z; v[7] = (__bf16)hi.w;
  return v;
}
// load 8 contiguous f32, round to bf16x8
__device__ __forceinline__ bf16x8 cvt8(const float* p) {
  return pack8(*(const float4*)p, *(const float4*)(p + 4));
}

// direct global->LDS, 16B/lane; LDS dest = wave-uniform base + lane*16
typedef __attribute__((address_space(1))) const unsigned int gu32;
typedef __attribute__((address_space(3))) unsigned int lu32;
__device__ __forceinline__ void async_copy16(const void* gp, void* lp) {
  __builtin_amdgcn_global_load_lds((gu32*)gp, (lu32*)lp, 16, 0, 0);
}

// f32 -> bf16 elementwise convert; grid.z selects tensor, grid.x*256*8 = count
__global__ __launch_bounds__(256) void cvt_kernel(
    const float* __restrict__ s0, uint16_t* __restrict__ d0,
    const float* __restrict__ s1, uint16_t* __restrict__ d1,
    const float* __restrict__ s2, uint16_t* __restrict__ d2,
    const float* __restrict__ s3, uint16_t* __restrict__ d3) {
  const int z = blockIdx.z;
  const float* s = z == 0 ? s0 : z == 1 ? s1 : z == 2 ? s2 : s3;
  uint16_t* d = z == 0 ? d0 : z == 1 ? d1 : z == 2 ? d2 : d3;
  const size_t idx = ((size_t)blockIdx.x * 256 + threadIdx.x) * 8;
  *(bf16x8*)(d + idx) = cvt8(s + idx);
}

// NT GEMM + bias: C[m,n] = sum_k A[m,k]*W[n,k] + bias[n]
// BM x (NF*32) tile, BK=64, 256 threads as 2m x 2n waves, acc[BM/32][NF].
// R14: pure-bf16 both-operand global_load_lds path (A_F32=W_F32=false) is
// the m97-proven config: 0.25 KB staged / MFMA. 128x128 QKV tile = 32KB
// LDS = 5 blocks/CU, zero reg staging. A_F32/W_F32 reg-staged paths
// retained for the ws_size<64MB fallback.
// LDS XOR-swizzled: conflict-free and contiguous rows. m-fastest block map
// for XCD L2 locality. ROPE fused into bf16 epilogue for dh<32.
// VT: z==2 writes C^T per-head.
template <bool A_F32, bool W_F32, bool C_F32, bool VT, bool ROPE, int BM, int NF>
__global__ __launch_bounds__(256) void gemm3_kernel(
    const void* __restrict__ A0, const void* __restrict__ W0,
    const float* __restrict__ b0, void* __restrict__ C0,
    const void* __restrict__ A1, const void* __restrict__ W1,
    const float* __restrict__ b1, void* __restrict__ C1,
    const void* __restrict__ A2, const void* __restrict__ W2,
    const float* __restrict__ b2, void* __restrict__ C2,
    int M, int N, int K) {
  constexpr int BN = NF * 32;
  constexpr int AF = BM / 32;   // A frags per wave, also A staging iters
  const int z = blockIdx.z;
  const void* Av = z == 0 ? A0 : z == 1 ? A1 : A2;
  const void* Wp = z == 0 ? W0 : z == 1 ? W1 : W2;
  const float* bias = z == 0 ? b0 : z == 1 ? b1 : b2;
  void* Cv = z == 0 ? C0 : z == 1 ? C1 : C2;

  __shared__ __align__(16) uint16_t As[BM * 64];
  __shared__ __align__(16) uint16_t Bs[BN * 64];
  const int tid = threadIdx.x;
  const int wave = tid >> 6, lane = tid & 63;
  const int quad = lane >> 4, l16 = lane & 15;
  // XCD-locality swizzle: m fastest in HW dispatch order
  const int l = blockIdx.y * gridDim.x + blockIdx.x;
  const int nmt = M / BM;
  const int bm = (l % nmt) * BM;
  const int bn = (l / nmt) * BN;
  const int wm = (wave >> 1) * (BM / 2);
  const int wn = (wave & 1) * (BN / 2);

  f32x4 acc[AF][NF] = {};

  for (int k0 = 0; k0 < K; k0 += 64) {
    bf16x8 ar[AF], wr[NF];
    if (A_F32) {
#pragma unroll
      for (int i = 0; i < AF; i++) {
        const int c = i * 256 + tid;
        const int r = c >> 3, pc = ((c & 7) ^ (r & 7)) << 3;
        ar[i] = cvt8((const float*)Av + (size_t)(bm + r) * K + k0 + pc);
      }
    }
    if (W_F32) {
#pragma unroll
      for (int i = 0; i < NF; i++) {
        const int c = i * 256 + tid;
        const int r = c >> 3, pc = ((c & 7) ^ (r & 7)) << 3;
        wr[i] = cvt8((const float*)Wp + (size_t)(bn + r) * K + k0 + pc);
      }
    }
    if (k0) __syncthreads();
#pragma unroll
    for (int i = 0; i < AF; i++) {
      const int c = i * 256 + tid;
      const int r = c >> 3, pc = ((c & 7) ^ (r & 7)) << 3;
      if (A_F32) *(bf16x8*)(As + c * 8) = ar[i];
      else async_copy16((const uint16_t*)Av + (size_t)(bm + r) * K + k0 + pc,
                        As + (i * 256 + (tid & 192)) * 8);
    }
#pragma unroll
    for (int i = 0; i < NF; i++) {
      const int c = i * 256 + tid;
      const int r = c >> 3, pc = ((c & 7) ^ (r & 7)) << 3;
      if (W_F32) *(bf16x8*)(Bs + c * 8) = wr[i];
      else async_copy16((const uint16_t*)Wp + (size_t)(bn + r) * K + k0 + pc,
                        Bs + (i * 256 + (tid & 192)) * 8);
    }
    __syncthreads();
#pragma unroll
    for (int s = 0; s < 2; s++) {
      bf16x8 af[AF], bfr[NF];
#pragma unroll
      for (int i = 0; i < AF; i++) {
        const int Ra = wm + i * 16 + l16;
        af[i] = *(const bf16x8*)(As + Ra * 64 + (((s * 4 + quad) ^ (Ra & 7)) << 3));
      }
#pragma unroll
      for (int j = 0; j < NF; j++) {
        const int Rb = wn + j * 16 + l16;
        bfr[j] = *(const bf16x8*)(Bs + Rb * 64 + (((s * 4 + quad) ^ (Rb & 7)) << 3));
      }
#pragma unroll
      for (int i = 0; i < AF; i++)
#pragma unroll
        for (int j = 0; j < NF; j++)
          acc[i][j] = __builtin_amdgcn_mfma_f32_16x16x32_bf16(af[i], bfr[j], acc[i][j], 0, 0, 0);
    }
  }
  if (VT && z == 2) {
#pragma unroll
    for (int j = 0; j < NF; j++) {
      const int n = bn + wn + j * 16 + l16;
      const float bj = bias[n];
      const int h = n >> 6, dh = n & 63;
#pragma unroll
      for (int i = 0; i < AF; i++) {
        const int m0 = bm + wm + i * 16 + quad * 4;
        const int b = m0 >> 11, s0 = m0 & 2047;
        uint2 pk;
        pk.x = (unsigned)f2bf(acc[i][j][0] + bj) |
               ((unsigned)f2bf(acc[i][j][1] + bj) << 16);
        pk.y = (unsigned)f2bf(acc[i][j][2] + bj) |
               ((unsigned)f2bf(acc[i][j][3] + bj) << 16);
        *(uint2*)((uint16_t*)Cv + ((size_t)((b * 16 + h) * 64 + dh)) * 2048 + s0) = pk;
      }
    }
  } else {
#pragma unroll
    for (int j = 0; j < NF; j++) {
      const int n = bn + wn + j * 16 + l16;
      const float bj = bias[n];
      // dh = n & 63; rot iff dh<32 — wave-uniform: ((wn + j*16) & 63) < 32
      const int dh = (wn + j * 16 + l16) & 63;
      const bool rot = ROPE && (((wn + j * 16) & 63) < 32);
      float invrev = 0.f;
      if (rot)
        invrev = __expf(-0.5756462732485115f * (float)(dh >> 1)) *
                 0.15915494309189535f;  // 10000^(-i/16) / 2pi
#pragma unroll
      for (int i = 0; i < AF; i++) {
        const int m0 = bm + wm + i * 16 + quad * 4;
#pragma unroll
        for (int r = 0; r < 4; r++) {
          float v = acc[i][j][r] + bj;
          if (rot) {
            const int s_pos = (m0 + r) & 2047;
            float rev = (float)s_pos * invrev;
            rev -= floorf(rev);
            const float sn = __builtin_amdgcn_sinf(rev);
            const float cs = __builtin_amdgcn_cosf(rev);
            const float partner = __shfl_xor(v, 1);
            v = (dh & 1) ? (v * cs + partner * sn) : (v * cs - partner * sn);
          }
          if (C_F32) ((float*)Cv)[(size_t)(m0 + r) * N + n] = v;
          else       ((uint16_t*)Cv)[(size_t)(m0 + r) * N + n] = f2bf(v);
        }
      }
    }
  }
}

// Flash attention, causal, MAX-FREE softmax (scores statically bounded ->
// exp finite; masked lanes -1e30 -> exp=0). S^T form: lane l16 owns q-row.
// R20: NS-way split-K + small-footprint blocks. R9 measured split-2 flash
// 55->47us but occupancy stuck at 16% (4 blocks/CU assigned AND VGPR-76
// rounds to 4 waves/SIMD). This round targets 6 resident blocks/CU:
//  - sequential frag processing (frag1 fully, then frag0) -> Ps halves to
//    9KB (LDS 25.6KB, 6 blocks by LDS) and only one sacc[4] live
//  - __launch_bounds__(256,6) pins allocator <=85 VGPR (6 waves/SIMD)
//  - NS=4: 2048 blocks = 8 assigned/CU. Co-resident 8-set (same w):
//    grp 0..7 -> (bh part grp&3, dir grp&1, seg-part grp>>2); per-set
//    kt total = nkt_desc + nkt_asc = 34 exactly, any w.
// Max-free softmax => partials combine LINEARLY (combine_kernel sums).
// NS=2 = R9 exact map (ws<96MB); NS=1 = non-split fallback.
template <int NS>
__global__ __launch_bounds__(256, 6) void flash_kernel(
    const uint16_t* __restrict__ Q, const uint16_t* __restrict__ K,
    const uint16_t* __restrict__ VT, uint16_t* __restrict__ AO,
    float* __restrict__ Po, float* __restrict__ Pl) {
  const int bx = blockIdx.x;           // NS=1:512  NS=2:1024  NS=4:2048
  const int xcd = bx & 7;
  const int s7 = bx >> 3;
  int bh, qt2, seg;
  if (NS == 1) {
    bh = (s7 >> 4) * 8 + xcd;
    qt2 = (s7 < 32) ? (15 - (s7 & 15)) : (s7 & 15);
    seg = 0;
  } else if (NS == 2) {
    const int grp = s7 >> 5, w = s7 & 31;
    bh = grp * 8 + xcd;
    qt2 = (grp & 1) ? (w & 15) : (15 - (w & 15));
    seg = w >> 4;
  } else {
    const int grp = s7 >> 5, w = s7 & 31;   // grp 0..7
    bh = (grp & 3) * 8 + xcd;
    qt2 = (grp & 1) ? (w & 15) : (15 - (w & 15));
    seg = (w >> 4) * 2 + (grp >> 2);
  }
  const int h = bh & 15;
  const int b = bh >> 4;
  const int tid = threadIdx.x;
  const int wave = tid >> 6, lane = tid & 63;
  const int quad = lane >> 4, l16 = lane & 15;

  __shared__ __align__(16) uint16_t Ks[64 * 64];      // [n][d] swizzled, 8KB
  __shared__ __align__(16) uint16_t Vt[64 * 64];      // [d][n] swizzled, 8KB
  __shared__ __align__(16) uint16_t Ps[4][16 * 72];   // per-wave P, 9KB

  // Q fragments (B-operand layout: lane l16 = q-row); pre-scale folds
  // 1/sqrt(64) * log2(e) so softmax is a bare exp2.
  const float QS = 0.18033688011112042f;
  const int qrow0 = qt2 * 128 + wave * 16 + l16;      // frag0
  const int qrow1 = qrow0 + 64;                       // frag1
  bf16x8 qf0[2], qf1[2];
#pragma unroll
  for (int s = 0; s < 2; s++) {
    union { bf16x8 v; uint16_t u[8]; } t0, t1;
    t0.v = *(const bf16x8*)(Q + ((size_t)(b * 2048 + qrow0) * 1024) + h * 64 + s * 32 + quad * 8);
    t1.v = *(const bf16x8*)(Q + ((size_t)(b * 2048 + qrow1) * 1024) + h * 64 + s * 32 + quad * 8);
#pragma unroll
    for (int j = 0; j < 8; j++) {
      t0.u[j] = f2bf(bf2f(t0.u[j]) * QS);
      t1.u[j] = f2bf(bf2f(t1.u[j]) * QS);
    }
    qf0[s] = t0.v;
    qf1[s] = t1.v;
  }

  const size_t vbase = ((size_t)((b * 16 + h) * 64)) * 2048;  // VT head base

  float lsum0 = 0.f, lsum1 = 0.f;
  f32x4 o0[4] = {}, o1[4] = {};

  const int nkt = 2 * qt2 + 2;
  const int k0b = (NS == 1) ? 0 : seg * nkt / NS;
  const int k0e = (NS == 1) ? nkt : (seg + 1) * nkt / NS;
  for (int kt = k0b; kt < k0e; kt++) {
    if (kt != k0b) __syncthreads();
#pragma unroll
    for (int i = 0; i < 2; i++) {
      const int c = i * 256 + tid;
      const int r = c >> 3, pc = ((c & 7) ^ (r & 7)) << 3;
      async_copy16(K + ((size_t)(b * 2048 + kt * 64 + r) * 1024) + h * 64 + pc,
                   Ks + (i * 256 + (tid & 192)) * 8);
      async_copy16(VT + vbase + (size_t)r * 2048 + kt * 64 + pc,
                   Vt + (i * 256 + (tid & 192)) * 8);
    }
    __syncthreads();

    const bool f0 = (kt < nkt - 1);  // low frag fully masked at last kt

    // ---- frag1: S^T -> softmax -> PV (Ps rows reused by frag0 after) ----
    {
      f32x4 sacc[4] = {};
#pragma unroll
      for (int s = 0; s < 2; s++)
#pragma unroll
        for (int t = 0; t < 4; t++) {
          const int R = t * 16 + l16;
          bf16x8 kf = *(const bf16x8*)(Ks + R * 64 + (((s * 4 + quad) ^ (R & 7)) << 3));
          sacc[t] = __builtin_amdgcn_mfma_f32_16x16x32_bf16(kf, qf1[s], sacc[t], 0, 0, 0);
        }
      if (kt == nkt - 1) {
#pragma unroll
        for (int t = 0; t < 4; t++)
#pragma unroll
          for (int r = 0; r < 4; r++)
            if (kt * 64 + t * 16 + quad * 4 + r > qrow1) sacc[t][r] = -1e30f;
      }
#pragma unroll
      for (int t = 0; t < 4; t++) {
        float p0 = __builtin_amdgcn_exp2f(sacc[t][0]);
        float p1 = __builtin_amdgcn_exp2f(sacc[t][1]);
        float p2 = __builtin_amdgcn_exp2f(sacc[t][2]);
        float p3 = __builtin_amdgcn_exp2f(sacc[t][3]);
        lsum1 += (p0 + p1) + (p2 + p3);
        uint2 pk;
        pk.x = (unsigned)f2bf(p0) | ((unsigned)f2bf(p1) << 16);
        pk.y = (unsigned)f2bf(p2) | ((unsigned)f2bf(p3) << 16);
        *(uint2*)(&Ps[wave][l16 * 72 + t * 16 + quad * 4]) = pk;
      }
#pragma unroll
      for (int s = 0; s < 2; s++) {
        const bf16x8 pa = *(const bf16x8*)(&Ps[wave][l16 * 72 + s * 32 + quad * 8]);
#pragma unroll
        for (int t = 0; t < 4; t++) {
          const int R = t * 16 + l16;
          const bf16x8 vb = *(const bf16x8*)(Vt + R * 64 + (((s * 4 + quad) ^ (R & 7)) << 3));
          o1[t] = __builtin_amdgcn_mfma_f32_16x16x32_bf16(pa, vb, o1[t], 0, 0, 0);
        }
      }
    }
    // ---- frag0 ----
    if (f0) {
      f32x4 sacc[4] = {};
#pragma unroll
      for (int s = 0; s < 2; s++)
#pragma unroll
        for (int t = 0; t < 4; t++) {
          const int R = t * 16 + l16;
          bf16x8 kf = *(const bf16x8*)(Ks + R * 64 + (((s * 4 + quad) ^ (R & 7)) << 3));
          sacc[t] = __builtin_amdgcn_mfma_f32_16x16x32_bf16(kf, qf0[s], sacc[t], 0, 0, 0);
        }
      if (kt == nkt - 2) {
#pragma unroll
        for (int t = 0; t < 4; t++)
#pragma unroll
          for (int r = 0; r < 4; r++)
            if (kt * 64 + t * 16 + quad * 4 + r > qrow0) sacc[t][r] = -1e30f;
      }
#pragma unroll
      for (int t = 0; t < 4; t++) {
        float p0 = __builtin_amdgcn_exp2f(sacc[t][0]);
        float p1 = __builtin_amdgcn_exp2f(sacc[t][1]);
        float p2 = __builtin_amdgcn_exp2f(sacc[t][2]);
        float p3 = __builtin_amdgcn_exp2f(sacc[t][3]);
        lsum0 += (p0 + p1) + (p2 + p3);
        uint2 pk;
        pk.x = (unsigned)f2bf(p0) | ((unsigned)f2bf(p1) << 16);
        pk.y = (unsigned)f2bf(p2) | ((unsigned)f2bf(p3) << 16);
        *(uint2*)(&Ps[wave][l16 * 72 + t * 16 + quad * 4]) = pk;
      }
#pragma unroll
      for (int s = 0; s < 2; s++) {
        const bf16x8 pa = *(const bf16x8*)(&Ps[wave][l16 * 72 + s * 32 + quad * 8]);
#pragma unroll
        for (int t = 0; t < 4; t++) {
          const int R = t * 16 + l16;
          const bf16x8 vb = *(const bf16x8*)(Vt + R * 64 + (((s * 4 + quad) ^ (R & 7)) << 3));
          o0[t] = __builtin_amdgcn_mfma_f32_16x16x32_bf16(pa, vb, o0[t], 0, 0, 0);
        }
      }
    }
  }
  // row-sum reduce over quads (q-row = l16)
  lsum0 += __shfl_xor(lsum0, 16);
  lsum0 += __shfl_xor(lsum0, 32);
  lsum1 += __shfl_xor(lsum1, 16);
  lsum1 += __shfl_xor(lsum1, 32);

  if (NS > 1) {
    // write unnormalized partials: o (f32) + per-row lsum
    const int pidx = (bh * 16 + qt2) * NS + seg;
    float* po = Po + (size_t)pidx * 8192;
#pragma unroll
    for (int t = 0; t < 4; t++)
#pragma unroll
      for (int r = 0; r < 4; r++) {
        const int row = wave * 16 + quad * 4 + r;
        po[row * 64 + t * 16 + l16] = o0[t][r];
        po[(row + 64) * 64 + t * 16 + l16] = o1[t][r];
      }
    if (lane < 16) {
      Pl[pidx * 128 + wave * 16 + l16] = lsum0;
      Pl[pidx * 128 + 64 + wave * 16 + l16] = lsum1;
    }
  } else {
    const float inv0 = 1.f / lsum0, inv1 = 1.f / lsum1;
    float invr0[4], invr1[4];
#pragma unroll
    for (int r = 0; r < 4; r++) {
      invr0[r] = __shfl(inv0, quad * 4 + r);
      invr1[r] = __shfl(inv1, quad * 4 + r);
    }
#pragma unroll
    for (int t = 0; t < 4; t++)
#pragma unroll
      for (int r = 0; r < 4; r++) {
        const int qg0 = qt2 * 128 + wave * 16 + quad * 4 + r;
        AO[((size_t)(b * 2048 + qg0) * 1024) + h * 64 + t * 16 + l16] =
            f2bf(o0[t][r] * invr0[r]);
        AO[((size_t)(b * 2048 + qg0 + 64) * 1024) + h * 64 + t * 16 + l16] =
            f2bf(o1[t][r] * invr1[r]);
      }
  }
}

// combine split-K partials: AO[row] = (sum_j o_j) / (sum_j lsum_j)
// 512 blocks (bh, qt2) x 256 threads (2 threads/row, 32 cols each)
template <int NS>
__global__ __launch_bounds__(256) void combine_kernel(
    const float* __restrict__ Po, const float* __restrict__ Pl,
    uint16_t* __restrict__ AO) {
  const int cb = blockIdx.x;
  const int bh = cb >> 4, qt2 = cb & 15;
  const int b = bh >> 4, h = bh & 15;
  const int tid = threadIdx.x;
  const int row = tid >> 1;
  const int c0 = (tid & 1) * 32;
  const int p0 = (bh * 16 + qt2) * NS;
  float ls = 0.f;
#pragma unroll
  for (int j = 0; j < NS; j++) ls += Pl[(p0 + j) * 128 + row];
  const float inv = 1.f / ls;
  uint16_t* dst = AO + ((size_t)(b * 2048 + qt2 * 128 + row) * 1024) + h * 64 + c0;
#pragma unroll
  for (int i = 0; i < 4; i++) {
    float a0 = 0, a1 = 0, a2 = 0, a3 = 0, a4 = 0, a5 = 0, a6 = 0, a7 = 0;
#pragma unroll
    for (int j = 0; j < NS; j++) {
      const float* p = Po + (size_t)(p0 + j) * 8192 + row * 64 + c0 + i * 8;
      const float4 x = ((const float4*)p)[0], y = ((const float4*)p)[1];
      a0 += x.x; a1 += x.y; a2 += x.z; a3 += x.w;
      a4 += y.x; a5 += y.y; a6 += y.z; a7 += y.w;
    }
    bf16x8 v;
    v[0] = (__bf16)(a0 * inv); v[1] = (__bf16)(a1 * inv);
    v[2] = (__bf16)(a2 * inv); v[3] = (__bf16)(a3 * inv);
    v[4] = (__bf16)(a4 * inv); v[5] = (__bf16)(a5 * inv);
    v[6] = (__bf16)(a6 * inv); v[7] = (__bf16)(a7 * inv);
    *(bf16x8*)(dst + i * 8) = v;
  }
}

extern "C" void kernel_launch(void* const* d_in, const int* in_sizes, int n_in,
                              void* d_out, int out_size, void* d_ws, size_t ws_size,
                              hipStream_t stream) {
  const float* query = (const float*)d_in[0];
  const float* key   = (const float*)d_in[1];
  const float* value = (const float*)d_in[2];
  const float* Wq = (const float*)d_in[3];
  const float* bq = (const float*)d_in[4];
  const float* Wk = (const float*)d_in[5];
  const float* bk = (const float*)d_in[6];
  const float* Wv = (const float*)d_in[7];
  const float* bv = (const float*)d_in[8];
  const float* Wo = (const float*)d_in[9];
  const float* bo = (const float*)d_in[10];
  float* out = (float*)d_out;

  uint16_t* ws = (uint16_t*)d_ws;
  uint16_t* Qb  = ws;                         // [0,8M) bytes: bf16 (roped)
  uint16_t* Kb  = ws + (size_t)4194304;       // [8M,16M) (roped)
  uint16_t* VTb = ws + (size_t)8388608;       // [16M,24M) V^T [b,h,d,s]

  dim3 blk(256);

  if (ws_size >= (size_t)64 * 1024 * 1024) {
    const bool big = ws_size >= (size_t)96 * 1024 * 1024;
    // Layout: [0,8M) Qb -> AOc (combine out; Qb dead). [8,16) Kb. [16,24) VTb.
    // [24,25M) Pl (NS=4: 1MB; NS=2 uses first 512KB). [25,27M) Woc.
    // [32,64M) Qc/Kc/Vc/Wqc/Wkc/Wvc (dead after QKV) -> Po partial o:
    //   NS=2: 32MB at [32,64M); NS=4: 64MB at [32,96M) (needs ws>=96MB).
    float*    Pl  = (float*)(ws + (size_t)12582912);   // byte 24M
    uint16_t* Woc = ws + (size_t)13107200;             // byte 25M
    uint16_t* Qc  = ws + (size_t)16777216;             // byte 32M
    uint16_t* Kc  = ws + (size_t)20971520;             // byte 40M
    uint16_t* Vc  = ws + (size_t)25165824;             // byte 48M
    uint16_t* Wqc = ws + (size_t)29360128;             // byte 56M
    uint16_t* Wkc = ws + (size_t)30408704;             // byte 58M
    uint16_t* Wvc = ws + (size_t)31457280;             // byte 60M
    float*    Po  = (float*)(ws + (size_t)16777216);   // byte 32M
    uint16_t* AOc = ws;                                 // over Qb

    cvt_kernel<<<dim3(512, 1, 4), blk, 0, stream>>>(
        Wq, Wqc, Wk, Wkc, Wv, Wvc, Wo, Woc);
    cvt_kernel<<<dim3(2048, 1, 3), blk, 0, stream>>>(
        query, Qc, key, Kc, value, Vc, nullptr, nullptr);
    // QKV: pure bf16, 128x128 tile, both operands global_load_lds
    gemm3_kernel<false, false, false, true, true, 128, 4><<<dim3(8, 32, 3), blk, 0, stream>>>(
        Qc, Wqc, bq, Qb,
        Kc, Wkc, bk, Kb,
        Vc, Wvc, bv, VTb,
        4096, 1024, 1024);
    if (big) {
      // 4-way split-K: 2048 blocks = 8 assigned / 6 resident per CU
      flash_kernel<4><<<dim3(2048), blk, 0, stream>>>(Qb, Kb, VTb, nullptr, Po, Pl);
      combine_kernel<4><<<dim3(512), blk, 0, stream>>>(Po, Pl, AOc);
    } else {
      // 2-way split-K (R9 measured config)
      flash_kernel<2><<<dim3(1024), blk, 0, stream>>>(Qb, Kb, VTb, nullptr, Po, Pl);
      combine_kernel<2><<<dim3(512), blk, 0, stream>>>(Po, Pl, AOc);
    }
    // out-proj: pure bf16 128x64, both DMA; A = combined attention out
    gemm3_kernel<false, false, true, false, false, 128, 2><<<dim3(16, 32, 1), blk, 0, stream>>>(
        AOc, Woc, bo, out,
        AOc, Woc, bo, out,
        AOc, Woc, bo, out,
        4096, 1024, 1024);
  } else {
    // Fallback: R0 GEMM configuration + non-split flash (32MB workspace).
    uint16_t* AOb = ws + (size_t)12582912;
    uint16_t* Wqc = AOb;
    uint16_t* Wkc = AOb + (size_t)1048576;
    uint16_t* Wvc = AOb + (size_t)2097152;
    cvt_kernel<<<dim3(512, 1, 3), blk, 0, stream>>>(
        Wq, Wqc, Wk, Wkc, Wv, Wvc, nullptr, nullptr);
    gemm3_kernel<true, false, false, true, true, 128, 2><<<dim3(16, 32, 3), blk, 0, stream>>>(
        query, Wqc, bq, Qb,
        key,   Wkc, bk, Kb,
        value, Wvc, bv, VTb,
        4096, 1024, 1024);
    flash_kernel<1><<<dim3(512), blk, 0, stream>>>(Qb, Kb, VTb, AOb, nullptr, nullptr);
    gemm3_kernel<false, true, true, false, false, 128, 2><<<dim3(16, 32, 1), blk, 0, stream>>>(
        AOb, Wo, bo, out,
        AOb, Wo, bo, out,
        AOb, Wo, bo, out,
        4096, 1024, 1024);
  }
}

// Round 11
// 241.900 us; speedup vs baseline: 1.3370x; 1.3370x over previous
//
#include <hip/hip_runtime.h>
#include <stdint.h>
#include <math.h>

// B=2 S=2048 E=1024 H=16 DH=64 ROT=32 CTX=2048
// d_in / d_out are FLOAT32 (per reference). Internals use bf16 MFMA.
typedef __bf16 bf16x8 __attribute__((ext_vector_type(8)));
typedef float f32x4 __attribute__((ext_vector_type(4)));

__device__ __forceinline__ float bf2f(uint16_t x) {
  unsigned u = ((unsigned)x) << 16;
  float f;
  __builtin_memcpy(&f, &u, 4);
  return f;
}
// native RTNE f32->bf16
__device__ __forceinline__ uint16_t f2bf(float f) {
  __bf16 h = (__bf16)f;
  uint16_t u;
  __builtin_memcpy(&u, &h, 2);
  return u;
}
// round two float4s to bf16x8
__device__ __forceinline__ bf16x8 pack8(float4 lo, float4 hi) {
  bf16x8 v;
  v[0] = (__bf16)lo.x; v[1] = (__bf16)lo.y; v[2] = (__bf16)lo.z; v[3] = (__bf16)lo.w;
  v[4] = (__bf16)hi.x; v[5] = (__bf16)hi.y; v[6] = (__bf16)hi.z; v[7] = (__bf16)hi.w;
  return v;
}
// load 8 contiguous f32, round to bf16x8
__device__ __forceinline__ bf16x8 cvt8(const float* p) {
  return pack8(*(const float4*)p, *(const float4*)(p + 4));
}

// direct global->LDS, 16B/lane; LDS dest = wave-uniform base + lane*16
typedef __attribute__((address_space(1))) const unsigned int gu32;
typedef __attribute__((address_space(3))) unsigned int lu32;
__device__ __forceinline__ void async_copy16(const void* gp, void* lp) {
  __builtin_amdgcn_global_load_lds((gu32*)gp, (lu32*)lp, 16, 0, 0);
}

// f32 -> bf16 elementwise convert; grid.z selects tensor, grid.x*256*8 = count
// (fallback path only)
__global__ __launch_bounds__(256) void cvt_kernel(
    const float* __restrict__ s0, uint16_t* __restrict__ d0,
    const float* __restrict__ s1, uint16_t* __restrict__ d1,
    const float* __restrict__ s2, uint16_t* __restrict__ d2,
    const float* __restrict__ s3, uint16_t* __restrict__ d3) {
  const int z = blockIdx.z;
  const float* s = z == 0 ? s0 : z == 1 ? s1 : z == 2 ? s2 : s3;
  uint16_t* d = z == 0 ? d0 : z == 1 ? d1 : z == 2 ? d2 : d3;
  const size_t idx = ((size_t)blockIdx.x * 256 + threadIdx.x) * 8;
  *(bf16x8*)(d + idx) = cvt8(s + idx);
}

// R21: ALL 7 f32->bf16 conversions in ONE launch (R8<->R9 launch-count
// deltas show ~3-5us per dispatch). grid (2048,1,4): z<3 = q/k/v (4M elems
// each); z=3 = weights, blockIdx.x>>9 selects Wq/Wk/Wv/Wo (1M elems each).
__global__ __launch_bounds__(256) void cvt_all_kernel(
    const float* __restrict__ q, uint16_t* __restrict__ qo,
    const float* __restrict__ k, uint16_t* __restrict__ ko,
    const float* __restrict__ v, uint16_t* __restrict__ vo,
    const float* __restrict__ w0, uint16_t* __restrict__ w0o,
    const float* __restrict__ w1, uint16_t* __restrict__ w1o,
    const float* __restrict__ w2, uint16_t* __restrict__ w2o,
    const float* __restrict__ w3, uint16_t* __restrict__ w3o) {
  const int z = blockIdx.z;
  const float* s;
  uint16_t* d;
  size_t idx;
  if (z < 3) {
    s = z == 0 ? q : z == 1 ? k : v;
    d = z == 0 ? qo : z == 1 ? ko : vo;
    idx = ((size_t)blockIdx.x * 256 + threadIdx.x) * 8;
  } else {
    const int w = blockIdx.x >> 9;
    s = w == 0 ? w0 : w == 1 ? w1 : w == 2 ? w2 : w3;
    d = w == 0 ? w0o : w == 1 ? w1o : w == 2 ? w2o : w3o;
    idx = ((size_t)(blockIdx.x & 511) * 256 + threadIdx.x) * 8;
  }
  *(bf16x8*)(d + idx) = cvt8(s + idx);
}

// NT GEMM + bias: C[m,n] = sum_k A[m,k]*W[n,k] + bias[n]
// BM x (NF*32) tile, BK=64, 256 threads as 2m x 2n waves, acc[BM/32][NF].
// R14: pure-bf16 both-operand global_load_lds path (A_F32=W_F32=false) is
// the m97-proven config: 0.25 KB staged / MFMA. 128x128 QKV tile = 32KB
// LDS = 5 blocks/CU, zero reg staging. A_F32/W_F32 reg-staged paths
// retained for the ws_size<64MB fallback.
// LDS XOR-swizzled: conflict-free and contiguous rows. m-fastest block map
// for XCD L2 locality. ROPE fused into bf16 epilogue for dh<32.
// VT: z==2 writes C^T per-head.
template <bool A_F32, bool W_F32, bool C_F32, bool VT, bool ROPE, int BM, int NF>
__global__ __launch_bounds__(256) void gemm3_kernel(
    const void* __restrict__ A0, const void* __restrict__ W0,
    const float* __restrict__ b0, void* __restrict__ C0,
    const void* __restrict__ A1, const void* __restrict__ W1,
    const float* __restrict__ b1, void* __restrict__ C1,
    const void* __restrict__ A2, const void* __restrict__ W2,
    const float* __restrict__ b2, void* __restrict__ C2,
    int M, int N, int K) {
  constexpr int BN = NF * 32;
  constexpr int AF = BM / 32;   // A frags per wave, also A staging iters
  const int z = blockIdx.z;
  const void* Av = z == 0 ? A0 : z == 1 ? A1 : A2;
  const void* Wp = z == 0 ? W0 : z == 1 ? W1 : W2;
  const float* bias = z == 0 ? b0 : z == 1 ? b1 : b2;
  void* Cv = z == 0 ? C0 : z == 1 ? C1 : C2;

  __shared__ __align__(16) uint16_t As[BM * 64];
  __shared__ __align__(16) uint16_t Bs[BN * 64];
  const int tid = threadIdx.x;
  const int wave = tid >> 6, lane = tid & 63;
  const int quad = lane >> 4, l16 = lane & 15;
  // XCD-locality swizzle: m fastest in HW dispatch order
  const int l = blockIdx.y * gridDim.x + blockIdx.x;
  const int nmt = M / BM;
  const int bm = (l % nmt) * BM;
  const int bn = (l / nmt) * BN;
  const int wm = (wave >> 1) * (BM / 2);
  const int wn = (wave & 1) * (BN / 2);

  f32x4 acc[AF][NF] = {};

  for (int k0 = 0; k0 < K; k0 += 64) {
    bf16x8 ar[AF], wr[NF];
    if (A_F32) {
#pragma unroll
      for (int i = 0; i < AF; i++) {
        const int c = i * 256 + tid;
        const int r = c >> 3, pc = ((c & 7) ^ (r & 7)) << 3;
        ar[i] = cvt8((const float*)Av + (size_t)(bm + r) * K + k0 + pc);
      }
    }
    if (W_F32) {
#pragma unroll
      for (int i = 0; i < NF; i++) {
        const int c = i * 256 + tid;
        const int r = c >> 3, pc = ((c & 7) ^ (r & 7)) << 3;
        wr[i] = cvt8((const float*)Wp + (size_t)(bn + r) * K + k0 + pc);
      }
    }
    if (k0) __syncthreads();
#pragma unroll
    for (int i = 0; i < AF; i++) {
      const int c = i * 256 + tid;
      const int r = c >> 3, pc = ((c & 7) ^ (r & 7)) << 3;
      if (A_F32) *(bf16x8*)(As + c * 8) = ar[i];
      else async_copy16((const uint16_t*)Av + (size_t)(bm + r) * K + k0 + pc,
                        As + (i * 256 + (tid & 192)) * 8);
    }
#pragma unroll
    for (int i = 0; i < NF; i++) {
      const int c = i * 256 + tid;
      const int r = c >> 3, pc = ((c & 7) ^ (r & 7)) << 3;
      if (W_F32) *(bf16x8*)(Bs + c * 8) = wr[i];
      else async_copy16((const uint16_t*)Wp + (size_t)(bn + r) * K + k0 + pc,
                        Bs + (i * 256 + (tid & 192)) * 8);
    }
    __syncthreads();
#pragma unroll
    for (int s = 0; s < 2; s++) {
      bf16x8 af[AF], bfr[NF];
#pragma unroll
      for (int i = 0; i < AF; i++) {
        const int Ra = wm + i * 16 + l16;
        af[i] = *(const bf16x8*)(As + Ra * 64 + (((s * 4 + quad) ^ (Ra & 7)) << 3));
      }
#pragma unroll
      for (int j = 0; j < NF; j++) {
        const int Rb = wn + j * 16 + l16;
        bfr[j] = *(const bf16x8*)(Bs + Rb * 64 + (((s * 4 + quad) ^ (Rb & 7)) << 3));
      }
#pragma unroll
      for (int i = 0; i < AF; i++)
#pragma unroll
        for (int j = 0; j < NF; j++)
          acc[i][j] = __builtin_amdgcn_mfma_f32_16x16x32_bf16(af[i], bfr[j], acc[i][j], 0, 0, 0);
    }
  }
  if (VT && z == 2) {
#pragma unroll
    for (int j = 0; j < NF; j++) {
      const int n = bn + wn + j * 16 + l16;
      const float bj = bias[n];
      const int h = n >> 6, dh = n & 63;
#pragma unroll
      for (int i = 0; i < AF; i++) {
        const int m0 = bm + wm + i * 16 + quad * 4;
        const int b = m0 >> 11, s0 = m0 & 2047;
        uint2 pk;
        pk.x = (unsigned)f2bf(acc[i][j][0] + bj) |
               ((unsigned)f2bf(acc[i][j][1] + bj) << 16);
        pk.y = (unsigned)f2bf(acc[i][j][2] + bj) |
               ((unsigned)f2bf(acc[i][j][3] + bj) << 16);
        *(uint2*)((uint16_t*)Cv + ((size_t)((b * 16 + h) * 64 + dh)) * 2048 + s0) = pk;
      }
    }
  } else {
#pragma unroll
    for (int j = 0; j < NF; j++) {
      const int n = bn + wn + j * 16 + l16;
      const float bj = bias[n];
      // dh = n & 63; rot iff dh<32 — wave-uniform: ((wn + j*16) & 63) < 32
      const int dh = (wn + j * 16 + l16) & 63;
      const bool rot = ROPE && (((wn + j * 16) & 63) < 32);
      float invrev = 0.f;
      if (rot)
        invrev = __expf(-0.5756462732485115f * (float)(dh >> 1)) *
                 0.15915494309189535f;  // 10000^(-i/16) / 2pi
#pragma unroll
      for (int i = 0; i < AF; i++) {
        const int m0 = bm + wm + i * 16 + quad * 4;
#pragma unroll
        for (int r = 0; r < 4; r++) {
          float v = acc[i][j][r] + bj;
          if (rot) {
            const int s_pos = (m0 + r) & 2047;
            float rev = (float)s_pos * invrev;
            rev -= floorf(rev);
            const float sn = __builtin_amdgcn_sinf(rev);
            const float cs = __builtin_amdgcn_cosf(rev);
            const float partner = __shfl_xor(v, 1);
            v = (dh & 1) ? (v * cs + partner * sn) : (v * cs - partner * sn);
          }
          if (C_F32) ((float*)Cv)[(size_t)(m0 + r) * N + n] = v;
          else       ((uint16_t*)Cv)[(size_t)(m0 + r) * N + n] = f2bf(v);
        }
      }
    }
  }
}

// Flash attention, causal, MAX-FREE softmax (scores statically bounded ->
// exp finite; masked lanes -1e30 -> exp=0). S^T form: lane l16 owns q-row.
// R21: R10 structure with the spill bug removed. R10's launch_bounds(256,6)
// forced VGPR 40 -> scratch spills (FETCH 181MB / WRITE 247MB, 123us).
// Default bounds: VGPR ~76 -> 6 waves/SIMD naturally; sequential frag
// processing keeps Ps at 9KB (LDS 25.6KB -> 6 blocks/CU by LDS); NS=4 grid
// 2048 = 8 assigned/CU -> ~6 resident. R10's NS=4 map + combine validated
// functionally (R10 passed). Max-free softmax => partials combine linearly.
template <int NS>
__global__ __launch_bounds__(256) void flash_kernel(
    const uint16_t* __restrict__ Q, const uint16_t* __restrict__ K,
    const uint16_t* __restrict__ VT, uint16_t* __restrict__ AO,
    float* __restrict__ Po, float* __restrict__ Pl) {
  const int bx = blockIdx.x;           // NS=1:512  NS=2:1024  NS=4:2048
  const int xcd = bx & 7;
  const int s7 = bx >> 3;
  int bh, qt2, seg;
  if (NS == 1) {
    bh = (s7 >> 4) * 8 + xcd;
    qt2 = (s7 < 32) ? (15 - (s7 & 15)) : (s7 & 15);
    seg = 0;
  } else if (NS == 2) {
    const int grp = s7 >> 5, w = s7 & 31;
    bh = grp * 8 + xcd;
    qt2 = (grp & 1) ? (w & 15) : (15 - (w & 15));
    seg = w >> 4;
  } else {
    const int grp = s7 >> 5, w = s7 & 31;   // grp 0..7
    bh = (grp & 3) * 8 + xcd;
    qt2 = (grp & 1) ? (w & 15) : (15 - (w & 15));
    seg = (w >> 4) * 2 + (grp >> 2);
  }
  const int h = bh & 15;
  const int b = bh >> 4;
  const int tid = threadIdx.x;
  const int wave = tid >> 6, lane = tid & 63;
  const int quad = lane >> 4, l16 = lane & 15;

  __shared__ __align__(16) uint16_t Ks[64 * 64];      // [n][d] swizzled, 8KB
  __shared__ __align__(16) uint16_t Vt[64 * 64];      // [d][n] swizzled, 8KB
  __shared__ __align__(16) uint16_t Ps[4][16 * 72];   // per-wave P, 9KB

  // Q fragments (B-operand layout: lane l16 = q-row); pre-scale folds
  // 1/sqrt(64) * log2(e) so softmax is a bare exp2.
  const float QS = 0.18033688011112042f;
  const int qrow0 = qt2 * 128 + wave * 16 + l16;      // frag0
  const int qrow1 = qrow0 + 64;                       // frag1
  bf16x8 qf0[2], qf1[2];
#pragma unroll
  for (int s = 0; s < 2; s++) {
    union { bf16x8 v; uint16_t u[8]; } t0, t1;
    t0.v = *(const bf16x8*)(Q + ((size_t)(b * 2048 + qrow0) * 1024) + h * 64 + s * 32 + quad * 8);
    t1.v = *(const bf16x8*)(Q + ((size_t)(b * 2048 + qrow1) * 1024) + h * 64 + s * 32 + quad * 8);
#pragma unroll
    for (int j = 0; j < 8; j++) {
      t0.u[j] = f2bf(bf2f(t0.u[j]) * QS);
      t1.u[j] = f2bf(bf2f(t1.u[j]) * QS);
    }
    qf0[s] = t0.v;
    qf1[s] = t1.v;
  }

  const size_t vbase = ((size_t)((b * 16 + h) * 64)) * 2048;  // VT head base

  float lsum0 = 0.f, lsum1 = 0.f;
  f32x4 o0[4] = {}, o1[4] = {};

  const int nkt = 2 * qt2 + 2;
  const int k0b = (NS == 1) ? 0 : seg * nkt / NS;
  const int k0e = (NS == 1) ? nkt : (seg + 1) * nkt / NS;
  for (int kt = k0b; kt < k0e; kt++) {
    if (kt != k0b) __syncthreads();
#pragma unroll
    for (int i = 0; i < 2; i++) {
      const int c = i * 256 + tid;
      const int r = c >> 3, pc = ((c & 7) ^ (r & 7)) << 3;
      async_copy16(K + ((size_t)(b * 2048 + kt * 64 + r) * 1024) + h * 64 + pc,
                   Ks + (i * 256 + (tid & 192)) * 8);
      async_copy16(VT + vbase + (size_t)r * 2048 + kt * 64 + pc,
                   Vt + (i * 256 + (tid & 192)) * 8);
    }
    __syncthreads();

    const bool f0 = (kt < nkt - 1);  // low frag fully masked at last kt

    // ---- frag1: S^T -> softmax -> PV (Ps rows reused by frag0 after) ----
    {
      f32x4 sacc[4] = {};
#pragma unroll
      for (int s = 0; s < 2; s++)
#pragma unroll
        for (int t = 0; t < 4; t++) {
          const int R = t * 16 + l16;
          bf16x8 kf = *(const bf16x8*)(Ks + R * 64 + (((s * 4 + quad) ^ (R & 7)) << 3));
          sacc[t] = __builtin_amdgcn_mfma_f32_16x16x32_bf16(kf, qf1[s], sacc[t], 0, 0, 0);
        }
      if (kt == nkt - 1) {
#pragma unroll
        for (int t = 0; t < 4; t++)
#pragma unroll
          for (int r = 0; r < 4; r++)
            if (kt * 64 + t * 16 + quad * 4 + r > qrow1) sacc[t][r] = -1e30f;
      }
#pragma unroll
      for (int t = 0; t < 4; t++) {
        float p0 = __builtin_amdgcn_exp2f(sacc[t][0]);
        float p1 = __builtin_amdgcn_exp2f(sacc[t][1]);
        float p2 = __builtin_amdgcn_exp2f(sacc[t][2]);
        float p3 = __builtin_amdgcn_exp2f(sacc[t][3]);
        lsum1 += (p0 + p1) + (p2 + p3);
        uint2 pk;
        pk.x = (unsigned)f2bf(p0) | ((unsigned)f2bf(p1) << 16);
        pk.y = (unsigned)f2bf(p2) | ((unsigned)f2bf(p3) << 16);
        *(uint2*)(&Ps[wave][l16 * 72 + t * 16 + quad * 4]) = pk;
      }
#pragma unroll
      for (int s = 0; s < 2; s++) {
        const bf16x8 pa = *(const bf16x8*)(&Ps[wave][l16 * 72 + s * 32 + quad * 8]);
#pragma unroll
        for (int t = 0; t < 4; t++) {
          const int R = t * 16 + l16;
          const bf16x8 vb = *(const bf16x8*)(Vt + R * 64 + (((s * 4 + quad) ^ (R & 7)) << 3));
          o1[t] = __builtin_amdgcn_mfma_f32_16x16x32_bf16(pa, vb, o1[t], 0, 0, 0);
        }
      }
    }
    // ---- frag0 ----
    if (f0) {
      f32x4 sacc[4] = {};
#pragma unroll
      for (int s = 0; s < 2; s++)
#pragma unroll
        for (int t = 0; t < 4; t++) {
          const int R = t * 16 + l16;
          bf16x8 kf = *(const bf16x8*)(Ks + R * 64 + (((s * 4 + quad) ^ (R & 7)) << 3));
          sacc[t] = __builtin_amdgcn_mfma_f32_16x16x32_bf16(kf, qf0[s], sacc[t], 0, 0, 0);
        }
      if (kt == nkt - 2) {
#pragma unroll
        for (int t = 0; t < 4; t++)
#pragma unroll
          for (int r = 0; r < 4; r++)
            if (kt * 64 + t * 16 + quad * 4 + r > qrow0) sacc[t][r] = -1e30f;
      }
#pragma unroll
      for (int t = 0; t < 4; t++) {
        float p0 = __builtin_amdgcn_exp2f(sacc[t][0]);
        float p1 = __builtin_amdgcn_exp2f(sacc[t][1]);
        float p2 = __builtin_amdgcn_exp2f(sacc[t][2]);
        float p3 = __builtin_amdgcn_exp2f(sacc[t][3]);
        lsum0 += (p0 + p1) + (p2 + p3);
        uint2 pk;
        pk.x = (unsigned)f2bf(p0) | ((unsigned)f2bf(p1) << 16);
        pk.y = (unsigned)f2bf(p2) | ((unsigned)f2bf(p3) << 16);
        *(uint2*)(&Ps[wave][l16 * 72 + t * 16 + quad * 4]) = pk;
      }
#pragma unroll
      for (int s = 0; s < 2; s++) {
        const bf16x8 pa = *(const bf16x8*)(&Ps[wave][l16 * 72 + s * 32 + quad * 8]);
#pragma unroll
        for (int t = 0; t < 4; t++) {
          const int R = t * 16 + l16;
          const bf16x8 vb = *(const bf16x8*)(Vt + R * 64 + (((s * 4 + quad) ^ (R & 7)) << 3));
          o0[t] = __builtin_amdgcn_mfma_f32_16x16x32_bf16(pa, vb, o0[t], 0, 0, 0);
        }
      }
    }
  }
  // row-sum reduce over quads (q-row = l16)
  lsum0 += __shfl_xor(lsum0, 16);
  lsum0 += __shfl_xor(lsum0, 32);
  lsum1 += __shfl_xor(lsum1, 16);
  lsum1 += __shfl_xor(lsum1, 32);

  if (NS > 1) {
    // write unnormalized partials: o (f32) + per-row lsum
    const int pidx = (bh * 16 + qt2) * NS + seg;
    float* po = Po + (size_t)pidx * 8192;
#pragma unroll
    for (int t = 0; t < 4; t++)
#pragma unroll
      for (int r = 0; r < 4; r++) {
        const int row = wave * 16 + quad * 4 + r;
        po[row * 64 + t * 16 + l16] = o0[t][r];
        po[(row + 64) * 64 + t * 16 + l16] = o1[t][r];
      }
    if (lane < 16) {
      Pl[pidx * 128 + wave * 16 + l16] = lsum0;
      Pl[pidx * 128 + 64 + wave * 16 + l16] = lsum1;
    }
  } else {
    const float inv0 = 1.f / lsum0, inv1 = 1.f / lsum1;
    float invr0[4], invr1[4];
#pragma unroll
    for (int r = 0; r < 4; r++) {
      invr0[r] = __shfl(inv0, quad * 4 + r);
      invr1[r] = __shfl(inv1, quad * 4 + r);
    }
#pragma unroll
    for (int t = 0; t < 4; t++)
#pragma unroll
      for (int r = 0; r < 4; r++) {
        const int qg0 = qt2 * 128 + wave * 16 + quad * 4 + r;
        AO[((size_t)(b * 2048 + qg0) * 1024) + h * 64 + t * 16 + l16] =
            f2bf(o0[t][r] * invr0[r]);
        AO[((size_t)(b * 2048 + qg0 + 64) * 1024) + h * 64 + t * 16 + l16] =
            f2bf(o1[t][r] * invr1[r]);
      }
  }
}

// combine split-K partials: AO[row] = (sum_j o_j) / (sum_j lsum_j)
// 512 blocks (bh, qt2) x 256 threads (2 threads/row, 32 cols each)
template <int NS>
__global__ __launch_bounds__(256) void combine_kernel(
    const float* __restrict__ Po, const float* __restrict__ Pl,
    uint16_t* __restrict__ AO) {
  const int cb = blockIdx.x;
  const int bh = cb >> 4, qt2 = cb & 15;
  const int b = bh >> 4, h = bh & 15;
  const int tid = threadIdx.x;
  const int row = tid >> 1;
  const int c0 = (tid & 1) * 32;
  const int p0 = (bh * 16 + qt2) * NS;
  float ls = 0.f;
#pragma unroll
  for (int j = 0; j < NS; j++) ls += Pl[(p0 + j) * 128 + row];
  const float inv = 1.f / ls;
  uint16_t* dst = AO + ((size_t)(b * 2048 + qt2 * 128 + row) * 1024) + h * 64 + c0;
#pragma unroll
  for (int i = 0; i < 4; i++) {
    float a0 = 0, a1 = 0, a2 = 0, a3 = 0, a4 = 0, a5 = 0, a6 = 0, a7 = 0;
#pragma unroll
    for (int j = 0; j < NS; j++) {
      const float* p = Po + (size_t)(p0 + j) * 8192 + row * 64 + c0 + i * 8;
      const float4 x = ((const float4*)p)[0], y = ((const float4*)p)[1];
      a0 += x.x; a1 += x.y; a2 += x.z; a3 += x.w;
      a4 += y.x; a5 += y.y; a6 += y.z; a7 += y.w;
    }
    bf16x8 v;
    v[0] = (__bf16)(a0 * inv); v[1] = (__bf16)(a1 * inv);
    v[2] = (__bf16)(a2 * inv); v[3] = (__bf16)(a3 * inv);
    v[4] = (__bf16)(a4 * inv); v[5] = (__bf16)(a5 * inv);
    v[6] = (__bf16)(a6 * inv); v[7] = (__bf16)(a7 * inv);
    *(bf16x8*)(dst + i * 8) = v;
  }
}

extern "C" void kernel_launch(void* const* d_in, const int* in_sizes, int n_in,
                              void* d_out, int out_size, void* d_ws, size_t ws_size,
                              hipStream_t stream) {
  const float* query = (const float*)d_in[0];
  const float* key   = (const float*)d_in[1];
  const float* value = (const float*)d_in[2];
  const float* Wq = (const float*)d_in[3];
  const float* bq = (const float*)d_in[4];
  const float* Wk = (const float*)d_in[5];
  const float* bk = (const float*)d_in[6];
  const float* Wv = (const float*)d_in[7];
  const float* bv = (const float*)d_in[8];
  const float* Wo = (const float*)d_in[9];
  const float* bo = (const float*)d_in[10];
  float* out = (float*)d_out;

  uint16_t* ws = (uint16_t*)d_ws;
  uint16_t* Qb  = ws;                         // [0,8M) bytes: bf16 (roped)
  uint16_t* Kb  = ws + (size_t)4194304;       // [8M,16M) (roped)
  uint16_t* VTb = ws + (size_t)8388608;       // [16M,24M) V^T [b,h,d,s]

  dim3 blk(256);

  if (ws_size >= (size_t)64 * 1024 * 1024) {
    const bool big = ws_size >= (size_t)96 * 1024 * 1024;
    // Layout: [0,8M) Qb -> AOc (combine out; Qb dead). [8,16) Kb. [16,24) VTb.
    // [24,25M) Pl (NS=4: 1MB). [25,27M) Woc.
    // [32,64M) Qc/Kc/Vc/Wqc/Wkc/Wvc (dead after QKV) -> Po partial o:
    //   NS=2: 32MB at [32,64M); NS=4: 64MB at [32,96M) (needs ws>=96MB).
    float*    Pl  = (float*)(ws + (size_t)12582912);   // byte 24M
    uint16_t* Woc = ws + (size_t)13107200;             // byte 25M
    uint16_t* Qc  = ws + (size_t)16777216;             // byte 32M
    uint16_t* Kc  = ws + (size_t)20971520;             // byte 40M
    uint16_t* Vc  = ws + (size_t)25165824;             // byte 48M
    uint16_t* Wqc = ws + (size_t)29360128;             // byte 56M
    uint16_t* Wkc = ws + (size_t)30408704;             // byte 58M
    uint16_t* Wvc = ws + (size_t)31457280;             // byte 60M
    float*    Po  = (float*)(ws + (size_t)16777216);   // byte 32M
    uint16_t* AOc = ws;                                 // over Qb

    // single cvt pass for all 7 tensors
    cvt_all_kernel<<<dim3(2048, 1, 4), blk, 0, stream>>>(
        query, Qc, key, Kc, value, Vc,
        Wq, Wqc, Wk, Wkc, Wv, Wvc, Wo, Woc);
    // QKV: pure bf16, 128x128 tile, both operands global_load_lds
    gemm3_kernel<false, false, false, true, true, 128, 4><<<dim3(8, 32, 3), blk, 0, stream>>>(
        Qc, Wqc, bq, Qb,
        Kc, Wkc, bk, Kb,
        Vc, Wvc, bv, VTb,
        4096, 1024, 1024);
    if (big) {
      // 4-way split-K: 2048 blocks, ~6 resident/CU (default launch bounds)
      flash_kernel<4><<<dim3(2048), blk, 0, stream>>>(Qb, Kb, VTb, nullptr, Po, Pl);
      combine_kernel<4><<<dim3(512), blk, 0, stream>>>(Po, Pl, AOc);
    } else {
      // 2-way split-K (R9 measured config)
      flash_kernel<2><<<dim3(1024), blk, 0, stream>>>(Qb, Kb, VTb, nullptr, Po, Pl);
      combine_kernel<2><<<dim3(512), blk, 0, stream>>>(Po, Pl, AOc);
    }
    // out-proj: pure bf16 128x64, both DMA; A = combined attention out
    gemm3_kernel<false, false, true, false, false, 128, 2><<<dim3(16, 32, 1), blk, 0, stream>>>(
        AOc, Woc, bo, out,
        AOc, Woc, bo, out,
        AOc, Woc, bo, out,
        4096, 1024, 1024);
  } else {
    // Fallback: R0 GEMM configuration + non-split flash (32MB workspace).
    uint16_t* AOb = ws + (size_t)12582912;
    uint16_t* Wqc = AOb;
    uint16_t* Wkc = AOb + (size_t)1048576;
    uint16_t* Wvc = AOb + (size_t)2097152;
    cvt_kernel<<<dim3(512, 1, 3), blk, 0, stream>>>(
        Wq, Wqc, Wk, Wkc, Wv, Wvc, nullptr, nullptr);
    gemm3_kernel<true, false, false, true, true, 128, 2><<<dim3(16, 32, 3), blk, 0, stream>>>(
        query, Wqc, bq, Qb,
        key,   Wkc, bk, Kb,
        value, Wvc, bv, VTb,
        4096, 1024, 1024);
    flash_kernel<1><<<dim3(512), blk, 0, stream>>>(Qb, Kb, VTb, AOb, nullptr, nullptr);
    gemm3_kernel<false, true, true, false, false, 128, 2><<<dim3(16, 32, 1), blk, 0, stream>>>(
        AOb, Wo, bo, out,
        AOb, Wo, bo, out,
        AOb, Wo, bo, out,
        4096, 1024, 1024);
  }
}

// Round 12
// 216.629 us; speedup vs baseline: 1.4929x; 1.1167x over previous
//
#include <hip/hip_runtime.h>
#include <stdint.h>
#include <math.h>

// B=2 S=2048 E=1024 H=16 DH=64 ROT=32 CTX=2048
// d_in / d_out are FLOAT32 (per reference). Internals use bf16 MFMA.
typedef __bf16 bf16x8 __attribute__((ext_vector_type(8)));
typedef float f32x4 __attribute__((ext_vector_type(4)));

__device__ __forceinline__ float bf2f(uint16_t x) {
  unsigned u = ((unsigned)x) << 16;
  float f;
  __builtin_memcpy(&f, &u, 4);
  return f;
}
// native RTNE f32->bf16
__device__ __forceinline__ uint16_t f2bf(float f) {
  __bf16 h = (__bf16)f;
  uint16_t u;
  __builtin_memcpy(&u, &h, 2);
  return u;
}
// round two float4s to bf16x8
__device__ __forceinline__ bf16x8 pack8(float4 lo, float4 hi) {
  bf16x8 v;
  v[0] = (__bf16)lo.x; v[1] = (__bf16)lo.y; v[2] = (__bf16)lo.z; v[3] = (__bf16)lo.w;
  v[4] = (__bf16)hi.x; v[5] = (__bf16)hi.y; v[6] = (__bf16)hi.z; v[7] = (__bf16)hi.w;
  return v;
}
// load 8 contiguous f32, round to bf16x8
__device__ __forceinline__ bf16x8 cvt8(const float* p) {
  return pack8(*(const float4*)p, *(const float4*)(p + 4));
}

// direct global->LDS, 16B/lane; LDS dest = wave-uniform base + lane*16
typedef __attribute__((address_space(1))) const unsigned int gu32;
typedef __attribute__((address_space(3))) unsigned int lu32;
__device__ __forceinline__ void async_copy16(const void* gp, void* lp) {
  __builtin_amdgcn_global_load_lds((gu32*)gp, (lu32*)lp, 16, 0, 0);
}

// f32 -> bf16 elementwise convert; grid.z selects tensor (fallback path)
__global__ __launch_bounds__(256) void cvt_kernel(
    const float* __restrict__ s0, uint16_t* __restrict__ d0,
    const float* __restrict__ s1, uint16_t* __restrict__ d1,
    const float* __restrict__ s2, uint16_t* __restrict__ d2,
    const float* __restrict__ s3, uint16_t* __restrict__ d3) {
  const int z = blockIdx.z;
  const float* s = z == 0 ? s0 : z == 1 ? s1 : z == 2 ? s2 : s3;
  uint16_t* d = z == 0 ? d0 : z == 1 ? d1 : z == 2 ? d2 : d3;
  const size_t idx = ((size_t)blockIdx.x * 256 + threadIdx.x) * 8;
  *(bf16x8*)(d + idx) = cvt8(s + idx);
}

// ALL 7 f32->bf16 conversions in ONE launch. grid (2048,1,4): z<3 = q/k/v
// (4M elems each); z=3 = weights, blockIdx.x>>9 selects Wq/Wk/Wv/Wo.
__global__ __launch_bounds__(256) void cvt_all_kernel(
    const float* __restrict__ q, uint16_t* __restrict__ qo,
    const float* __restrict__ k, uint16_t* __restrict__ ko,
    const float* __restrict__ v, uint16_t* __restrict__ vo,
    const float* __restrict__ w0, uint16_t* __restrict__ w0o,
    const float* __restrict__ w1, uint16_t* __restrict__ w1o,
    const float* __restrict__ w2, uint16_t* __restrict__ w2o,
    const float* __restrict__ w3, uint16_t* __restrict__ w3o) {
  const int z = blockIdx.z;
  const float* s;
  uint16_t* d;
  size_t idx;
  if (z < 3) {
    s = z == 0 ? q : z == 1 ? k : v;
    d = z == 0 ? qo : z == 1 ? ko : vo;
    idx = ((size_t)blockIdx.x * 256 + threadIdx.x) * 8;
  } else {
    const int w = blockIdx.x >> 9;
    s = w == 0 ? w0 : w == 1 ? w1 : w == 2 ? w2 : w3;
    d = w == 0 ? w0o : w == 1 ? w1o : w == 2 ? w2o : w3o;
    idx = ((size_t)(blockIdx.x & 511) * 256 + threadIdx.x) * 8;
  }
  *(bf16x8*)(d + idx) = cvt8(s + idx);
}

// NT GEMM + bias: C[m,n] = sum_k A[m,k]*W[n,k] + bias[n]
// BM x (NF*32) tile, BK=64, 256 threads as 2m x 2n waves, acc[BM/32][NF].
// Pure-bf16 both-operand global_load_lds path (A_F32=W_F32=false) is the
// m97-proven config: 0.25 KB staged / MFMA (R3: dur tracks staged-bytes-
// per-MFMA). 128x128 QKV tile = 32KB LDS, zero reg staging. A_F32/W_F32
// reg-staged paths retained for the ws_size<64MB fallback.
// LDS XOR-swizzled: conflict-free, contiguous rows. m-fastest block map
// for XCD L2 locality. ROPE fused into bf16 epilogue for dh<32.
// VT: z==2 writes C^T per-head.
template <bool A_F32, bool W_F32, bool C_F32, bool VT, bool ROPE, int BM, int NF>
__global__ __launch_bounds__(256) void gemm3_kernel(
    const void* __restrict__ A0, const void* __restrict__ W0,
    const float* __restrict__ b0, void* __restrict__ C0,
    const void* __restrict__ A1, const void* __restrict__ W1,
    const float* __restrict__ b1, void* __restrict__ C1,
    const void* __restrict__ A2, const void* __restrict__ W2,
    const float* __restrict__ b2, void* __restrict__ C2,
    int M, int N, int K) {
  constexpr int BN = NF * 32;
  constexpr int AF = BM / 32;   // A frags per wave, also A staging iters
  const int z = blockIdx.z;
  const void* Av = z == 0 ? A0 : z == 1 ? A1 : A2;
  const void* Wp = z == 0 ? W0 : z == 1 ? W1 : W2;
  const float* bias = z == 0 ? b0 : z == 1 ? b1 : b2;
  void* Cv = z == 0 ? C0 : z == 1 ? C1 : C2;

  __shared__ __align__(16) uint16_t As[BM * 64];
  __shared__ __align__(16) uint16_t Bs[BN * 64];
  const int tid = threadIdx.x;
  const int wave = tid >> 6, lane = tid & 63;
  const int quad = lane >> 4, l16 = lane & 15;
  // XCD-locality swizzle: m fastest in HW dispatch order
  const int l = blockIdx.y * gridDim.x + blockIdx.x;
  const int nmt = M / BM;
  const int bm = (l % nmt) * BM;
  const int bn = (l / nmt) * BN;
  const int wm = (wave >> 1) * (BM / 2);
  const int wn = (wave & 1) * (BN / 2);

  f32x4 acc[AF][NF] = {};

  for (int k0 = 0; k0 < K; k0 += 64) {
    bf16x8 ar[AF], wr[NF];
    if (A_F32) {
#pragma unroll
      for (int i = 0; i < AF; i++) {
        const int c = i * 256 + tid;
        const int r = c >> 3, pc = ((c & 7) ^ (r & 7)) << 3;
        ar[i] = cvt8((const float*)Av + (size_t)(bm + r) * K + k0 + pc);
      }
    }
    if (W_F32) {
#pragma unroll
      for (int i = 0; i < NF; i++) {
        const int c = i * 256 + tid;
        const int r = c >> 3, pc = ((c & 7) ^ (r & 7)) << 3;
        wr[i] = cvt8((const float*)Wp + (size_t)(bn + r) * K + k0 + pc);
      }
    }
    if (k0) __syncthreads();
#pragma unroll
    for (int i = 0; i < AF; i++) {
      const int c = i * 256 + tid;
      const int r = c >> 3, pc = ((c & 7) ^ (r & 7)) << 3;
      if (A_F32) *(bf16x8*)(As + c * 8) = ar[i];
      else async_copy16((const uint16_t*)Av + (size_t)(bm + r) * K + k0 + pc,
                        As + (i * 256 + (tid & 192)) * 8);
    }
#pragma unroll
    for (int i = 0; i < NF; i++) {
      const int c = i * 256 + tid;
      const int r = c >> 3, pc = ((c & 7) ^ (r & 7)) << 3;
      if (W_F32) *(bf16x8*)(Bs + c * 8) = wr[i];
      else async_copy16((const uint16_t*)Wp + (size_t)(bn + r) * K + k0 + pc,
                        Bs + (i * 256 + (tid & 192)) * 8);
    }
    __syncthreads();
#pragma unroll
    for (int s = 0; s < 2; s++) {
      bf16x8 af[AF], bfr[NF];
#pragma unroll
      for (int i = 0; i < AF; i++) {
        const int Ra = wm + i * 16 + l16;
        af[i] = *(const bf16x8*)(As + Ra * 64 + (((s * 4 + quad) ^ (Ra & 7)) << 3));
      }
#pragma unroll
      for (int j = 0; j < NF; j++) {
        const int Rb = wn + j * 16 + l16;
        bfr[j] = *(const bf16x8*)(Bs + Rb * 64 + (((s * 4 + quad) ^ (Rb & 7)) << 3));
      }
#pragma unroll
      for (int i = 0; i < AF; i++)
#pragma unroll
        for (int j = 0; j < NF; j++)
          acc[i][j] = __builtin_amdgcn_mfma_f32_16x16x32_bf16(af[i], bfr[j], acc[i][j], 0, 0, 0);
    }
  }
  if (VT && z == 2) {
#pragma unroll
    for (int j = 0; j < NF; j++) {
      const int n = bn + wn + j * 16 + l16;
      const float bj = bias[n];
      const int h = n >> 6, dh = n & 63;
#pragma unroll
      for (int i = 0; i < AF; i++) {
        const int m0 = bm + wm + i * 16 + quad * 4;
        const int b = m0 >> 11, s0 = m0 & 2047;
        uint2 pk;
        pk.x = (unsigned)f2bf(acc[i][j][0] + bj) |
               ((unsigned)f2bf(acc[i][j][1] + bj) << 16);
        pk.y = (unsigned)f2bf(acc[i][j][2] + bj) |
               ((unsigned)f2bf(acc[i][j][3] + bj) << 16);
        *(uint2*)((uint16_t*)Cv + ((size_t)((b * 16 + h) * 64 + dh)) * 2048 + s0) = pk;
      }
    }
  } else {
#pragma unroll
    for (int j = 0; j < NF; j++) {
      const int n = bn + wn + j * 16 + l16;
      const float bj = bias[n];
      // dh = n & 63; rot iff dh<32 — wave-uniform: ((wn + j*16) & 63) < 32
      const int dh = (wn + j * 16 + l16) & 63;
      const bool rot = ROPE && (((wn + j * 16) & 63) < 32);
      float invrev = 0.f;
      if (rot)
        invrev = __expf(-0.5756462732485115f * (float)(dh >> 1)) *
                 0.15915494309189535f;  // 10000^(-i/16) / 2pi
#pragma unroll
      for (int i = 0; i < AF; i++) {
        const int m0 = bm + wm + i * 16 + quad * 4;
#pragma unroll
        for (int r = 0; r < 4; r++) {
          float v = acc[i][j][r] + bj;
          if (rot) {
            const int s_pos = (m0 + r) & 2047;
            float rev = (float)s_pos * invrev;
            rev -= floorf(rev);
            const float sn = __builtin_amdgcn_sinf(rev);
            const float cs = __builtin_amdgcn_cosf(rev);
            const float partner = __shfl_xor(v, 1);
            v = (dh & 1) ? (v * cs + partner * sn) : (v * cs - partner * sn);
          }
          if (C_F32) ((float*)Cv)[(size_t)(m0 + r) * N + n] = v;
          else       ((uint16_t*)Cv)[(size_t)(m0 + r) * N + n] = f2bf(v);
        }
      }
    }
  }
}

// Flash attention, causal, MAX-FREE softmax (scores statically bounded ->
// exp finite; masked lanes -1e30 -> exp2=0). S^T form: lane l16 owns q-row.
// R22: PAIRED KV-TILE STAGING on the R8 measured-best body. R9-R11 ledger:
// flash-alone floor ~47us at any >=4 blocks/CU (concurrency saturated),
// combine tax >= its gain -> split-K abandoned; best total = R8 (flash<1>
// 55.2). The non-scaling cost is per-kt sync events (2 barriers + vmcnt
// drain). nkt = 2*qt2+2 is ALWAYS EVEN -> process kv tiles in PAIRS:
// stage Ks[2]/Vt[2] (32KB), one barrier pair per TWO tiles, compute both
// sub-tiles back-to-back. Sync events halve; compute window per drain
// doubles; staged bytes/MFMA unchanged (R3/R5 invariant). LDS 50KB -> 3
// blocks/CU capacity >= grid's 2. No combine, no partials.
// R22b: log2e folded into Q pre-scale -> bare v_exp_f32 (exp2) softmax
// (validated R9-R11). Complementary pairing (R8): co-resident slots
// (s, s+32) sum to exactly 36 kt -> per-CU balance.
// 128 q-rows per block (2 Q-frags per wave); low frag skipped at last kt.
// XCD swizzle: bx&7 = XCD; 4 heads/XCD -> 2 MB K/VT L2-resident.
__global__ __launch_bounds__(256) void flash_kernel(const uint16_t* __restrict__ Q,
                                                    const uint16_t* __restrict__ K,
                                                    const uint16_t* __restrict__ VT,
                                                    uint16_t* __restrict__ AO) {
  const int bx = blockIdx.x;           // 512 blocks
  const int xcd = bx & 7;
  const int slot = bx >> 3;            // 0..63 within XCD
  const int bh = (slot >> 4) * 8 + xcd;
  // complementary pairing: slot s (desc) and s+32 (asc) sum to 36 kt
  const int qt2 = (slot < 32) ? (15 - (slot & 15)) : (slot & 15);
  const int h = bh & 15;
  const int b = bh >> 4;
  const int tid = threadIdx.x;
  const int wave = tid >> 6, lane = tid & 63;
  const int quad = lane >> 4, l16 = lane & 15;

  __shared__ __align__(16) uint16_t Ks[2][64 * 64];   // [n][d] swizzled, 16KB
  __shared__ __align__(16) uint16_t Vt[2][64 * 64];   // [d][n] swizzled, 16KB
  __shared__ __align__(16) uint16_t Ps[4][32 * 72];   // per-wave P, 18KB

  // Q fragments (B-operand layout: lane l16 = q-row); pre-scale folds
  // 1/sqrt(64) * log2(e) so softmax is a bare exp2.
  const float QS = 0.18033688011112042f;
  const int qrow0 = qt2 * 128 + wave * 16 + l16;      // frag0
  const int qrow1 = qrow0 + 64;                       // frag1
  bf16x8 qf0[2], qf1[2];
#pragma unroll
  for (int s = 0; s < 2; s++) {
    union { bf16x8 v; uint16_t u[8]; } t0, t1;
    t0.v = *(const bf16x8*)(Q + ((size_t)(b * 2048 + qrow0) * 1024) + h * 64 + s * 32 + quad * 8);
    t1.v = *(const bf16x8*)(Q + ((size_t)(b * 2048 + qrow1) * 1024) + h * 64 + s * 32 + quad * 8);
#pragma unroll
    for (int j = 0; j < 8; j++) {
      t0.u[j] = f2bf(bf2f(t0.u[j]) * QS);
      t1.u[j] = f2bf(bf2f(t1.u[j]) * QS);
    }
    qf0[s] = t0.v;
    qf1[s] = t1.v;
  }

  const size_t vbase = ((size_t)((b * 16 + h) * 64)) * 2048;  // VT head base

  float lsum0 = 0.f, lsum1 = 0.f;
  f32x4 o0[4] = {}, o1[4] = {};

  const int nkt = 2 * qt2 + 2;                        // always even
  for (int outer = 0; outer < nkt; outer += 2) {
    if (outer) __syncthreads();
    // stage BOTH sub-tiles; one vmcnt drain covers all 16 DMAs
#pragma unroll
    for (int i = 0; i < 2; i++) {
      const int c = i * 256 + tid;
      const int r = c >> 3, pc = ((c & 7) ^ (r & 7)) << 3;
      const int ld = (i * 256 + (tid & 192)) * 8;
#pragma unroll
      for (int sub = 0; sub < 2; sub++) {
        const int kt = outer + sub;
        async_copy16(K + ((size_t)(b * 2048 + kt * 64 + r) * 1024) + h * 64 + pc,
                     Ks[sub] + ld);
        async_copy16(VT + vbase + (size_t)r * 2048 + kt * 64 + pc,
                     Vt[sub] + ld);
      }
    }
    __syncthreads();

#pragma unroll
    for (int sub = 0; sub < 2; sub++) {
      const int kt = outer + sub;
      const uint16_t* ksp = Ks[sub];
      const uint16_t* vtp = Vt[sub];
      const bool f0 = (kt < nkt - 1);  // low frag fully masked at last kt

      // ---- frag1 S^T ----
      {
        f32x4 sacc[4] = {};
#pragma unroll
        for (int s = 0; s < 2; s++)
#pragma unroll
          for (int t = 0; t < 4; t++) {
            const int R = t * 16 + l16;
            bf16x8 kf = *(const bf16x8*)(ksp + R * 64 + (((s * 4 + quad) ^ (R & 7)) << 3));
            sacc[t] = __builtin_amdgcn_mfma_f32_16x16x32_bf16(kf, qf1[s], sacc[t], 0, 0, 0);
          }
        if (kt == nkt - 1) {
#pragma unroll
          for (int t = 0; t < 4; t++)
#pragma unroll
            for (int r = 0; r < 4; r++)
              if (kt * 64 + t * 16 + quad * 4 + r > qrow1) sacc[t][r] = -1e30f;
        }
#pragma unroll
        for (int t = 0; t < 4; t++) {
          float p0 = __builtin_amdgcn_exp2f(sacc[t][0]);
          float p1 = __builtin_amdgcn_exp2f(sacc[t][1]);
          float p2 = __builtin_amdgcn_exp2f(sacc[t][2]);
          float p3 = __builtin_amdgcn_exp2f(sacc[t][3]);
          lsum1 += (p0 + p1) + (p2 + p3);
          uint2 pk;
          pk.x = (unsigned)f2bf(p0) | ((unsigned)f2bf(p1) << 16);
          pk.y = (unsigned)f2bf(p2) | ((unsigned)f2bf(p3) << 16);
          *(uint2*)(&Ps[wave][(16 + l16) * 72 + t * 16 + quad * 4]) = pk;
        }
      }
      // ---- frag0 S^T ----
      if (f0) {
        f32x4 sacc[4] = {};
#pragma unroll
        for (int s = 0; s < 2; s++)
#pragma unroll
          for (int t = 0; t < 4; t++) {
            const int R = t * 16 + l16;
            bf16x8 kf = *(const bf16x8*)(ksp + R * 64 + (((s * 4 + quad) ^ (R & 7)) << 3));
            sacc[t] = __builtin_amdgcn_mfma_f32_16x16x32_bf16(kf, qf0[s], sacc[t], 0, 0, 0);
          }
        if (kt == nkt - 2) {
#pragma unroll
          for (int t = 0; t < 4; t++)
#pragma unroll
            for (int r = 0; r < 4; r++)
              if (kt * 64 + t * 16 + quad * 4 + r > qrow0) sacc[t][r] = -1e30f;
        }
#pragma unroll
        for (int t = 0; t < 4; t++) {
          float p0 = __builtin_amdgcn_exp2f(sacc[t][0]);
          float p1 = __builtin_amdgcn_exp2f(sacc[t][1]);
          float p2 = __builtin_amdgcn_exp2f(sacc[t][2]);
          float p3 = __builtin_amdgcn_exp2f(sacc[t][3]);
          lsum0 += (p0 + p1) + (p2 + p3);
          uint2 pk;
          pk.x = (unsigned)f2bf(p0) | ((unsigned)f2bf(p1) << 16);
          pk.y = (unsigned)f2bf(p2) | ((unsigned)f2bf(p3) << 16);
          *(uint2*)(&Ps[wave][l16 * 72 + t * 16 + quad * 4]) = pk;
        }
      }
      // ---- PV ----
#pragma unroll
      for (int s = 0; s < 2; s++) {
        const bf16x8 pa1 = *(const bf16x8*)(&Ps[wave][(16 + l16) * 72 + s * 32 + quad * 8]);
#pragma unroll
        for (int t = 0; t < 4; t++) {
          const int R = t * 16 + l16;
          const bf16x8 vb = *(const bf16x8*)(vtp + R * 64 + (((s * 4 + quad) ^ (R & 7)) << 3));
          o1[t] = __builtin_amdgcn_mfma_f32_16x16x32_bf16(pa1, vb, o1[t], 0, 0, 0);
        }
      }
      if (f0) {
#pragma unroll
        for (int s = 0; s < 2; s++) {
          const bf16x8 pa0 = *(const bf16x8*)(&Ps[wave][l16 * 72 + s * 32 + quad * 8]);
#pragma unroll
          for (int t = 0; t < 4; t++) {
            const int R = t * 16 + l16;
            const bf16x8 vb = *(const bf16x8*)(vtp + R * 64 + (((s * 4 + quad) ^ (R & 7)) << 3));
            o0[t] = __builtin_amdgcn_mfma_f32_16x16x32_bf16(pa0, vb, o0[t], 0, 0, 0);
          }
        }
      }
    }
  }
  // row-sum reduce over quads (q-row = l16); broadcast inverse to C/D rows
  lsum0 += __shfl_xor(lsum0, 16);
  lsum0 += __shfl_xor(lsum0, 32);
  lsum1 += __shfl_xor(lsum1, 16);
  lsum1 += __shfl_xor(lsum1, 32);
  const float inv0 = 1.f / lsum0, inv1 = 1.f / lsum1;
  float invr0[4], invr1[4];
#pragma unroll
  for (int r = 0; r < 4; r++) {
    invr0[r] = __shfl(inv0, quad * 4 + r);
    invr1[r] = __shfl(inv1, quad * 4 + r);
  }
#pragma unroll
  for (int t = 0; t < 4; t++)
#pragma unroll
    for (int r = 0; r < 4; r++) {
      const int qg0 = qt2 * 128 + wave * 16 + quad * 4 + r;
      AO[((size_t)(b * 2048 + qg0) * 1024) + h * 64 + t * 16 + l16] =
          f2bf(o0[t][r] * invr0[r]);
      AO[((size_t)(b * 2048 + qg0 + 64) * 1024) + h * 64 + t * 16 + l16] =
          f2bf(o1[t][r] * invr1[r]);
    }
}

extern "C" void kernel_launch(void* const* d_in, const int* in_sizes, int n_in,
                              void* d_out, int out_size, void* d_ws, size_t ws_size,
                              hipStream_t stream) {
  const float* query = (const float*)d_in[0];
  const float* key   = (const float*)d_in[1];
  const float* value = (const float*)d_in[2];
  const float* Wq = (const float*)d_in[3];
  const float* bq = (const float*)d_in[4];
  const float* Wk = (const float*)d_in[5];
  const float* bk = (const float*)d_in[6];
  const float* Wv = (const float*)d_in[7];
  const float* bv = (const float*)d_in[8];
  const float* Wo = (const float*)d_in[9];
  const float* bo = (const float*)d_in[10];
  float* out = (float*)d_out;

  uint16_t* ws = (uint16_t*)d_ws;
  uint16_t* Qb  = ws;                         // [0,8M) bytes: bf16 (roped)
  uint16_t* Kb  = ws + (size_t)4194304;       // [8M,16M) (roped)
  uint16_t* VTb = ws + (size_t)8388608;       // [16M,24M) V^T [b,h,d,s]
  uint16_t* AOb = ws + (size_t)12582912;      // [24M,32M)

  dim3 blk(256);

  if (ws_size >= (size_t)64 * 1024 * 1024) {
    // Fast path: bf16 copies of activations + all weights -> pure-DMA GEMMs.
    uint16_t* Qc  = ws + (size_t)16777216;    // [32M,40M) query bf16
    uint16_t* Kc  = ws + (size_t)20971520;    // [40M,48M) key bf16
    uint16_t* Vc  = ws + (size_t)25165824;    // [48M,56M) value bf16
    uint16_t* Wqc = ws + (size_t)29360128;    // [56M,58M)
    uint16_t* Wkc = ws + (size_t)30408704;    // [58M,60M)
    uint16_t* Wvc = ws + (size_t)31457280;    // [60M,62M)
    uint16_t* Woc = ws + (size_t)32505856;    // [62M,64M)

    // single cvt pass for all 7 tensors
    cvt_all_kernel<<<dim3(2048, 1, 4), blk, 0, stream>>>(
        query, Qc, key, Kc, value, Vc,
        Wq, Wqc, Wk, Wkc, Wv, Wvc, Wo, Woc);
    // QKV: pure bf16, 128x128 tile, both operands global_load_lds
    gemm3_kernel<false, false, false, true, true, 128, 4><<<dim3(8, 32, 3), blk, 0, stream>>>(
        Qc, Wqc, bq, Qb,
        Kc, Wkc, bk, Kb,
        Vc, Wvc, bv, VTb,
        4096, 1024, 1024);
    flash_kernel<<<dim3(512), blk, 0, stream>>>(Qb, Kb, VTb, AOb);
    // out-proj: pure bf16 128x64, both DMA
    gemm3_kernel<false, false, true, false, false, 128, 2><<<dim3(16, 32, 1), blk, 0, stream>>>(
        AOb, Woc, bo, out,
        AOb, Woc, bo, out,
        AOb, Woc, bo, out,
        4096, 1024, 1024);
  } else {
    // Fallback: R0 GEMM configuration (32MB workspace).
    uint16_t* Wqc = AOb;
    uint16_t* Wkc = AOb + (size_t)1048576;
    uint16_t* Wvc = AOb + (size_t)2097152;
    cvt_kernel<<<dim3(512, 1, 3), blk, 0, stream>>>(
        Wq, Wqc, Wk, Wkc, Wv, Wvc, nullptr, nullptr);
    gemm3_kernel<true, false, false, true, true, 128, 2><<<dim3(16, 32, 3), blk, 0, stream>>>(
        query, Wqc, bq, Qb,
        key,   Wkc, bk, Kb,
        value, Wvc, bv, VTb,
        4096, 1024, 1024);
    flash_kernel<<<dim3(512), blk, 0, stream>>>(Qb, Kb, VTb, AOb);
    gemm3_kernel<false, true, true, false, false, 128, 2><<<dim3(16, 32, 1), blk, 0, stream>>>(
        AOb, Wo, bo, out,
        AOb, Wo, bo, out,
        AOb, Wo, bo, out,
        4096, 1024, 1024);
  }
}

// Round 13
// 207.357 us; speedup vs baseline: 1.5597x; 1.0447x over previous
//
#include <hip/hip_runtime.h>
#include <stdint.h>
#include <math.h>

// B=2 S=2048 E=1024 H=16 DH=64 ROT=32 CTX=2048
// d_in / d_out are FLOAT32 (per reference). Internals use bf16 MFMA.
typedef __bf16 bf16x8 __attribute__((ext_vector_type(8)));
typedef float f32x4 __attribute__((ext_vector_type(4)));

__device__ __forceinline__ float bf2f(uint16_t x) {
  unsigned u = ((unsigned)x) << 16;
  float f;
  __builtin_memcpy(&f, &u, 4);
  return f;
}
// native RTNE f32->bf16
__device__ __forceinline__ uint16_t f2bf(float f) {
  __bf16 h = (__bf16)f;
  uint16_t u;
  __builtin_memcpy(&u, &h, 2);
  return u;
}
// round two float4s to bf16x8
__device__ __forceinline__ bf16x8 pack8(float4 lo, float4 hi) {
  bf16x8 v;
  v[0] = (__bf16)lo.x; v[1] = (__bf16)lo.y; v[2] = (__bf16)lo.z; v[3] = (__bf16)lo.w;
  v[4] = (__bf16)hi.x; v[5] = (__bf16)hi.y; v[6] = (__bf16)hi.z; v[7] = (__bf16)hi.w;
  return v;
}
// load 8 contiguous f32, round to bf16x8
__device__ __forceinline__ bf16x8 cvt8(const float* p) {
  return pack8(*(const float4*)p, *(const float4*)(p + 4));
}

// direct global->LDS, 16B/lane; LDS dest = wave-uniform base + lane*16
typedef __attribute__((address_space(1))) const unsigned int gu32;
typedef __attribute__((address_space(3))) unsigned int lu32;
__device__ __forceinline__ void async_copy16(const void* gp, void* lp) {
  __builtin_amdgcn_global_load_lds((gu32*)gp, (lu32*)lp, 16, 0, 0);
}

// f32 -> bf16 elementwise convert; grid.z selects tensor (fallback path)
__global__ __launch_bounds__(256) void cvt_kernel(
    const float* __restrict__ s0, uint16_t* __restrict__ d0,
    const float* __restrict__ s1, uint16_t* __restrict__ d1,
    const float* __restrict__ s2, uint16_t* __restrict__ d2,
    const float* __restrict__ s3, uint16_t* __restrict__ d3) {
  const int z = blockIdx.z;
  const float* s = z == 0 ? s0 : z == 1 ? s1 : z == 2 ? s2 : s3;
  uint16_t* d = z == 0 ? d0 : z == 1 ? d1 : z == 2 ? d2 : d3;
  const size_t idx = ((size_t)blockIdx.x * 256 + threadIdx.x) * 8;
  *(bf16x8*)(d + idx) = cvt8(s + idx);
}

// ALL 7 f32->bf16 conversions in ONE launch. grid (2048,1,4): z<3 = q/k/v
// (4M elems each); z=3 = weights, blockIdx.x>>9 selects Wq/Wk/Wv/Wo.
__global__ __launch_bounds__(256) void cvt_all_kernel(
    const float* __restrict__ q, uint16_t* __restrict__ qo,
    const float* __restrict__ k, uint16_t* __restrict__ ko,
    const float* __restrict__ v, uint16_t* __restrict__ vo,
    const float* __restrict__ w0, uint16_t* __restrict__ w0o,
    const float* __restrict__ w1, uint16_t* __restrict__ w1o,
    const float* __restrict__ w2, uint16_t* __restrict__ w2o,
    const float* __restrict__ w3, uint16_t* __restrict__ w3o) {
  const int z = blockIdx.z;
  const float* s;
  uint16_t* d;
  size_t idx;
  if (z < 3) {
    s = z == 0 ? q : z == 1 ? k : v;
    d = z == 0 ? qo : z == 1 ? ko : vo;
    idx = ((size_t)blockIdx.x * 256 + threadIdx.x) * 8;
  } else {
    const int w = blockIdx.x >> 9;
    s = w == 0 ? w0 : w == 1 ? w1 : w == 2 ? w2 : w3;
    d = w == 0 ? w0o : w == 1 ? w1o : w == 2 ? w2o : w3o;
    idx = ((size_t)(blockIdx.x & 511) * 256 + threadIdx.x) * 8;
  }
  *(bf16x8*)(d + idx) = cvt8(s + idx);
}

// NT GEMM + bias: C[m,n] = sum_k A[m,k]*W[n,k] + bias[n]
// BM x (NF*32) tile, BK=64, 256 threads as 2m x 2n waves, acc[BM/32][NF].
// Pure-bf16 both-operand global_load_lds path (A_F32=W_F32=false) is the
// m97-proven config: 0.25 KB staged / MFMA (R3: dur tracks staged-bytes-
// per-MFMA). 128x128 QKV tile = 32KB LDS, zero reg staging. A_F32/W_F32
// reg-staged paths retained for the ws_size<64MB fallback.
// LDS XOR-swizzled: conflict-free, contiguous rows. m-fastest block map
// for XCD L2 locality. ROPE fused into bf16 epilogue for dh<32.
// VT: z==2 writes C^T per-head.
template <bool A_F32, bool W_F32, bool C_F32, bool VT, bool ROPE, int BM, int NF>
__global__ __launch_bounds__(256) void gemm3_kernel(
    const void* __restrict__ A0, const void* __restrict__ W0,
    const float* __restrict__ b0, void* __restrict__ C0,
    const void* __restrict__ A1, const void* __restrict__ W1,
    const float* __restrict__ b1, void* __restrict__ C1,
    const void* __restrict__ A2, const void* __restrict__ W2,
    const float* __restrict__ b2, void* __restrict__ C2,
    int M, int N, int K) {
  constexpr int BN = NF * 32;
  constexpr int AF = BM / 32;   // A frags per wave, also A staging iters
  const int z = blockIdx.z;
  const void* Av = z == 0 ? A0 : z == 1 ? A1 : A2;
  const void* Wp = z == 0 ? W0 : z == 1 ? W1 : W2;
  const float* bias = z == 0 ? b0 : z == 1 ? b1 : b2;
  void* Cv = z == 0 ? C0 : z == 1 ? C1 : C2;

  __shared__ __align__(16) uint16_t As[BM * 64];
  __shared__ __align__(16) uint16_t Bs[BN * 64];
  const int tid = threadIdx.x;
  const int wave = tid >> 6, lane = tid & 63;
  const int quad = lane >> 4, l16 = lane & 15;
  // XCD-locality swizzle: m fastest in HW dispatch order
  const int l = blockIdx.y * gridDim.x + blockIdx.x;
  const int nmt = M / BM;
  const int bm = (l % nmt) * BM;
  const int bn = (l / nmt) * BN;
  const int wm = (wave >> 1) * (BM / 2);
  const int wn = (wave & 1) * (BN / 2);

  f32x4 acc[AF][NF] = {};

  for (int k0 = 0; k0 < K; k0 += 64) {
    bf16x8 ar[AF], wr[NF];
    if (A_F32) {
#pragma unroll
      for (int i = 0; i < AF; i++) {
        const int c = i * 256 + tid;
        const int r = c >> 3, pc = ((c & 7) ^ (r & 7)) << 3;
        ar[i] = cvt8((const float*)Av + (size_t)(bm + r) * K + k0 + pc);
      }
    }
    if (W_F32) {
#pragma unroll
      for (int i = 0; i < NF; i++) {
        const int c = i * 256 + tid;
        const int r = c >> 3, pc = ((c & 7) ^ (r & 7)) << 3;
        wr[i] = cvt8((const float*)Wp + (size_t)(bn + r) * K + k0 + pc);
      }
    }
    if (k0) __syncthreads();
#pragma unroll
    for (int i = 0; i < AF; i++) {
      const int c = i * 256 + tid;
      const int r = c >> 3, pc = ((c & 7) ^ (r & 7)) << 3;
      if (A_F32) *(bf16x8*)(As + c * 8) = ar[i];
      else async_copy16((const uint16_t*)Av + (size_t)(bm + r) * K + k0 + pc,
                        As + (i * 256 + (tid & 192)) * 8);
    }
#pragma unroll
    for (int i = 0; i < NF; i++) {
      const int c = i * 256 + tid;
      const int r = c >> 3, pc = ((c & 7) ^ (r & 7)) << 3;
      if (W_F32) *(bf16x8*)(Bs + c * 8) = wr[i];
      else async_copy16((const uint16_t*)Wp + (size_t)(bn + r) * K + k0 + pc,
                        Bs + (i * 256 + (tid & 192)) * 8);
    }
    __syncthreads();
#pragma unroll
    for (int s = 0; s < 2; s++) {
      bf16x8 af[AF], bfr[NF];
#pragma unroll
      for (int i = 0; i < AF; i++) {
        const int Ra = wm + i * 16 + l16;
        af[i] = *(const bf16x8*)(As + Ra * 64 + (((s * 4 + quad) ^ (Ra & 7)) << 3));
      }
#pragma unroll
      for (int j = 0; j < NF; j++) {
        const int Rb = wn + j * 16 + l16;
        bfr[j] = *(const bf16x8*)(Bs + Rb * 64 + (((s * 4 + quad) ^ (Rb & 7)) << 3));
      }
#pragma unroll
      for (int i = 0; i < AF; i++)
#pragma unroll
        for (int j = 0; j < NF; j++)
          acc[i][j] = __builtin_amdgcn_mfma_f32_16x16x32_bf16(af[i], bfr[j], acc[i][j], 0, 0, 0);
    }
  }
  if (VT && z == 2) {
#pragma unroll
    for (int j = 0; j < NF; j++) {
      const int n = bn + wn + j * 16 + l16;
      const float bj = bias[n];
      const int h = n >> 6, dh = n & 63;
#pragma unroll
      for (int i = 0; i < AF; i++) {
        const int m0 = bm + wm + i * 16 + quad * 4;
        const int b = m0 >> 11, s0 = m0 & 2047;
        uint2 pk;
        pk.x = (unsigned)f2bf(acc[i][j][0] + bj) |
               ((unsigned)f2bf(acc[i][j][1] + bj) << 16);
        pk.y = (unsigned)f2bf(acc[i][j][2] + bj) |
               ((unsigned)f2bf(acc[i][j][3] + bj) << 16);
        *(uint2*)((uint16_t*)Cv + ((size_t)((b * 16 + h) * 64 + dh)) * 2048 + s0) = pk;
      }
    }
  } else {
#pragma unroll
    for (int j = 0; j < NF; j++) {
      const int n = bn + wn + j * 16 + l16;
      const float bj = bias[n];
      // dh = n & 63; rot iff dh<32 — wave-uniform: ((wn + j*16) & 63) < 32
      const int dh = (wn + j * 16 + l16) & 63;
      const bool rot = ROPE && (((wn + j * 16) & 63) < 32);
      float invrev = 0.f;
      if (rot)
        invrev = __expf(-0.5756462732485115f * (float)(dh >> 1)) *
                 0.15915494309189535f;  // 10000^(-i/16) / 2pi
#pragma unroll
      for (int i = 0; i < AF; i++) {
        const int m0 = bm + wm + i * 16 + quad * 4;
#pragma unroll
        for (int r = 0; r < 4; r++) {
          float v = acc[i][j][r] + bj;
          if (rot) {
            const int s_pos = (m0 + r) & 2047;
            float rev = (float)s_pos * invrev;
            rev -= floorf(rev);
            const float sn = __builtin_amdgcn_sinf(rev);
            const float cs = __builtin_amdgcn_cosf(rev);
            const float partner = __shfl_xor(v, 1);
            v = (dh & 1) ? (v * cs + partner * sn) : (v * cs - partner * sn);
          }
          if (C_F32) ((float*)Cv)[(size_t)(m0 + r) * N + n] = v;
          else       ((uint16_t*)Cv)[(size_t)(m0 + r) * N + n] = f2bf(v);
        }
      }
    }
  }
}

// Flash attention, causal, MAX-FREE softmax (scores statically bounded ->
// exp2 finite; masked lanes -1e30 -> exp2=0). S^T form: lane l16 owns q-row.
// R23: 8-WAVE BLOCKS, ONE FRAG PER WAVE. R12's ledger: three different
// configs all floor at ~47us with 2 waves/SIMD and MfmaUtil+VALUBusy ~44%
// -> per-wave dependency-latency-bound. This round re-partitions the SAME
// 128-row block across 8 waves (one 16-row frag each) instead of 4 waves
// x 2 frags: staged bytes per block-kt UNCHANGED (R5's failure avoided),
// total MFMA/exp unchanged, but waves/SIMD 2->4 and each wave's per-kt
// chain halves -> 2x latency-hiding. Staging: 512 threads = exactly one
// async_copy16 per thread per tile (same swizzled layout). Causal logic
// generalizes wave-uniformly: skip iff kt*64 > qrowMax; mask iff
// kt*64+63 > qrowMin (reproduces old frag0/frag1 cases exactly).
// Paired KV staging kept (R12: sync halving = -7.6us). exp2 softmax via
// log2e-folded Q pre-scale (validated R9-R12). Complementary pairing
// (R8): co-resident slots (s, s+32) sum to exactly 36 kt.
// LDS 50KB: Ks[2]+Vt[2] 32KB + Ps 8x2.25KB. Grid 512 = 2 blocks/CU =
// 16 waves/CU. XCD swizzle: bx&7 = XCD; 4 heads/XCD -> K/VT L2-resident.
__global__ __launch_bounds__(512) void flash_kernel(const uint16_t* __restrict__ Q,
                                                    const uint16_t* __restrict__ K,
                                                    const uint16_t* __restrict__ VT,
                                                    uint16_t* __restrict__ AO) {
  const int bx = blockIdx.x;           // 512 blocks
  const int xcd = bx & 7;
  const int slot = bx >> 3;            // 0..63 within XCD
  const int bh = (slot >> 4) * 8 + xcd;
  // complementary pairing: slot s (desc) and s+32 (asc) sum to 36 kt
  const int qt2 = (slot < 32) ? (15 - (slot & 15)) : (slot & 15);
  const int h = bh & 15;
  const int b = bh >> 4;
  const int tid = threadIdx.x;         // 0..511
  const int wave = tid >> 6, lane = tid & 63;
  const int quad = lane >> 4, l16 = lane & 15;

  __shared__ __align__(16) uint16_t Ks[2][64 * 64];   // [n][d] swizzled, 16KB
  __shared__ __align__(16) uint16_t Vt[2][64 * 64];   // [d][n] swizzled, 16KB
  __shared__ __align__(16) uint16_t Ps[8][16 * 72];   // per-wave P, 18KB

  // Q fragment (B-operand layout: lane l16 = q-row); pre-scale folds
  // 1/sqrt(64) * log2(e) so softmax is a bare exp2.
  const float QS = 0.18033688011112042f;
  const int qrowMin = qt2 * 128 + wave * 16;          // wave-uniform
  const int qrowMax = qrowMin + 15;                   // wave-uniform
  const int qrow = qrowMin + l16;
  bf16x8 qf[2];
#pragma unroll
  for (int s = 0; s < 2; s++) {
    union { bf16x8 v; uint16_t u[8]; } t0;
    t0.v = *(const bf16x8*)(Q + ((size_t)(b * 2048 + qrow) * 1024) + h * 64 + s * 32 + quad * 8);
#pragma unroll
    for (int j = 0; j < 8; j++) t0.u[j] = f2bf(bf2f(t0.u[j]) * QS);
    qf[s] = t0.v;
  }

  const size_t vbase = ((size_t)((b * 16 + h) * 64)) * 2048;  // VT head base

  // staging decomposition for 512 threads: one 16B chunk per thread/tile
  const int sr = tid >> 3;                        // global row 0..63
  const int spc = ((tid & 7) ^ (sr & 7)) << 3;    // swizzled chunk (u16)
  const int sld = (tid & 448) * 8;                // wave-uniform LDS base

  float lsum = 0.f;
  f32x4 o[4] = {};

  const int nkt = 2 * qt2 + 2;                        // always even
  for (int outer = 0; outer < nkt; outer += 2) {
    if (outer) __syncthreads();
    // stage BOTH sub-tiles; one vmcnt drain covers all 4 DMAs/thread
#pragma unroll
    for (int sub = 0; sub < 2; sub++) {
      const int kt = outer + sub;
      async_copy16(K + ((size_t)(b * 2048 + kt * 64 + sr) * 1024) + h * 64 + spc,
                   Ks[sub] + sld);
      async_copy16(VT + vbase + (size_t)sr * 2048 + kt * 64 + spc,
                   Vt[sub] + sld);
    }
    __syncthreads();

#pragma unroll
    for (int sub = 0; sub < 2; sub++) {
      const int kt = outer + sub;
      if (kt * 64 > qrowMax) continue;   // fully masked for this wave
      const uint16_t* ksp = Ks[sub];
      const uint16_t* vtp = Vt[sub];

      // ---- S^T = K q^T ----
      f32x4 sacc[4] = {};
#pragma unroll
      for (int s = 0; s < 2; s++)
#pragma unroll
        for (int t = 0; t < 4; t++) {
          const int R = t * 16 + l16;
          bf16x8 kf = *(const bf16x8*)(ksp + R * 64 + (((s * 4 + quad) ^ (R & 7)) << 3));
          sacc[t] = __builtin_amdgcn_mfma_f32_16x16x32_bf16(kf, qf[s], sacc[t], 0, 0, 0);
        }
      if (kt * 64 + 63 > qrowMin) {      // diagonal-touching tile: mask
#pragma unroll
        for (int t = 0; t < 4; t++)
#pragma unroll
          for (int r = 0; r < 4; r++)
            if (kt * 64 + t * 16 + quad * 4 + r > qrow) sacc[t][r] = -1e30f;
      }
#pragma unroll
      for (int t = 0; t < 4; t++) {
        float p0 = __builtin_amdgcn_exp2f(sacc[t][0]);
        float p1 = __builtin_amdgcn_exp2f(sacc[t][1]);
        float p2 = __builtin_amdgcn_exp2f(sacc[t][2]);
        float p3 = __builtin_amdgcn_exp2f(sacc[t][3]);
        lsum += (p0 + p1) + (p2 + p3);
        uint2 pk;
        pk.x = (unsigned)f2bf(p0) | ((unsigned)f2bf(p1) << 16);
        pk.y = (unsigned)f2bf(p2) | ((unsigned)f2bf(p3) << 16);
        *(uint2*)(&Ps[wave][l16 * 72 + t * 16 + quad * 4]) = pk;
      }
      // ---- PV ----
#pragma unroll
      for (int s = 0; s < 2; s++) {
        const bf16x8 pa = *(const bf16x8*)(&Ps[wave][l16 * 72 + s * 32 + quad * 8]);
#pragma unroll
        for (int t = 0; t < 4; t++) {
          const int R = t * 16 + l16;
          const bf16x8 vb = *(const bf16x8*)(vtp + R * 64 + (((s * 4 + quad) ^ (R & 7)) << 3));
          o[t] = __builtin_amdgcn_mfma_f32_16x16x32_bf16(pa, vb, o[t], 0, 0, 0);
        }
      }
    }
  }
  // row-sum reduce over quads (q-row = l16); broadcast inverse to C/D rows
  lsum += __shfl_xor(lsum, 16);
  lsum += __shfl_xor(lsum, 32);
  const float inv = 1.f / lsum;
  float invr[4];
#pragma unroll
  for (int r = 0; r < 4; r++) invr[r] = __shfl(inv, quad * 4 + r);
#pragma unroll
  for (int t = 0; t < 4; t++)
#pragma unroll
    for (int r = 0; r < 4; r++) {
      const int qg = qrowMin + quad * 4 + r;
      AO[((size_t)(b * 2048 + qg) * 1024) + h * 64 + t * 16 + l16] =
          f2bf(o[t][r] * invr[r]);
    }
}

extern "C" void kernel_launch(void* const* d_in, const int* in_sizes, int n_in,
                              void* d_out, int out_size, void* d_ws, size_t ws_size,
                              hipStream_t stream) {
  const float* query = (const float*)d_in[0];
  const float* key   = (const float*)d_in[1];
  const float* value = (const float*)d_in[2];
  const float* Wq = (const float*)d_in[3];
  const float* bq = (const float*)d_in[4];
  const float* Wk = (const float*)d_in[5];
  const float* bk = (const float*)d_in[6];
  const float* Wv = (const float*)d_in[7];
  const float* bv = (const float*)d_in[8];
  const float* Wo = (const float*)d_in[9];
  const float* bo = (const float*)d_in[10];
  float* out = (float*)d_out;

  uint16_t* ws = (uint16_t*)d_ws;
  uint16_t* Qb  = ws;                         // [0,8M) bytes: bf16 (roped)
  uint16_t* Kb  = ws + (size_t)4194304;       // [8M,16M) (roped)
  uint16_t* VTb = ws + (size_t)8388608;       // [16M,24M) V^T [b,h,d,s]
  uint16_t* AOb = ws + (size_t)12582912;      // [24M,32M)

  dim3 blk(256);
  dim3 fblk(512);

  if (ws_size >= (size_t)64 * 1024 * 1024) {
    // Fast path: bf16 copies of activations + all weights -> pure-DMA GEMMs.
    uint16_t* Qc  = ws + (size_t)16777216;    // [32M,40M) query bf16
    uint16_t* Kc  = ws + (size_t)20971520;    // [40M,48M) key bf16
    uint16_t* Vc  = ws + (size_t)25165824;    // [48M,56M) value bf16
    uint16_t* Wqc = ws + (size_t)29360128;    // [56M,58M)
    uint16_t* Wkc = ws + (size_t)30408704;    // [58M,60M)
    uint16_t* Wvc = ws + (size_t)31457280;    // [60M,62M)
    uint16_t* Woc = ws + (size_t)32505856;    // [62M,64M)

    // single cvt pass for all 7 tensors
    cvt_all_kernel<<<dim3(2048, 1, 4), blk, 0, stream>>>(
        query, Qc, key, Kc, value, Vc,
        Wq, Wqc, Wk, Wkc, Wv, Wvc, Wo, Woc);
    // QKV: pure bf16, 128x128 tile, both operands global_load_lds
    gemm3_kernel<false, false, false, true, true, 128, 4><<<dim3(8, 32, 3), blk, 0, stream>>>(
        Qc, Wqc, bq, Qb,
        Kc, Wkc, bk, Kb,
        Vc, Wvc, bv, VTb,
        4096, 1024, 1024);
    flash_kernel<<<dim3(512), fblk, 0, stream>>>(Qb, Kb, VTb, AOb);
    // out-proj: pure bf16 128x64, both DMA
    gemm3_kernel<false, false, true, false, false, 128, 2><<<dim3(16, 32, 1), blk, 0, stream>>>(
        AOb, Woc, bo, out,
        AOb, Woc, bo, out,
        AOb, Woc, bo, out,
        4096, 1024, 1024);
  } else {
    // Fallback: R0 GEMM configuration (32MB workspace).
    uint16_t* Wqc = AOb;
    uint16_t* Wkc = AOb + (size_t)1048576;
    uint16_t* Wvc = AOb + (size_t)2097152;
    cvt_kernel<<<dim3(512, 1, 3), blk, 0, stream>>>(
        Wq, Wqc, Wk, Wkc, Wv, Wvc, nullptr, nullptr);
    gemm3_kernel<true, false, false, true, true, 128, 2><<<dim3(16, 32, 3), blk, 0, stream>>>(
        query, Wqc, bq, Qb,
        key,   Wkc, bk, Kb,
        value, Wvc, bv, VTb,
        4096, 1024, 1024);
    flash_kernel<<<dim3(512), fblk, 0, stream>>>(Qb, Kb, VTb, AOb);
    gemm3_kernel<false, true, true, false, false, 128, 2><<<dim3(16, 32, 1), blk, 0, stream>>>(
        AOb, Wo, bo, out,
        AOb, Wo, bo, out,
        AOb, Wo, bo, out,
        4096, 1024, 1024);
  }
}